// Round 4
// baseline (1290.924 us; speedup 1.0000x reference)
//
#include <hip/hip_runtime.h>

// ---------------------------------------------------------------------------
// NSA attention forward, B=1, S=2048, HID=2048, H=16, D=128, L=32, NB=64,
// NSEL=8, WIN=512.  f32 in/out.  bf16 MFMA compute (split hi/lo bf16 for the
// selection-critical Q/K projections; f32 VALU for selection-critical cmp
// scores).  Round 4: merged win+sel attention (atomicAdd combine), merged
// 3-way GEMM dispatch, defer-max softmax, 2-barrier loop, swizzled LDS.
// ---------------------------------------------------------------------------

#define SCALE_F 0.08838834764831845f                         // 1/sqrt(128)
#define SCL2E   (0.08838834764831845f * 1.4426950408889634f) // SCALE*log2(e)

typedef short  bf16x8 __attribute__((ext_vector_type(8)));
typedef short  s16x4  __attribute__((ext_vector_type(4)));
typedef float  f32x4  __attribute__((ext_vector_type(4)));

__device__ __forceinline__ unsigned short f2bfu(float x){
    unsigned u = __builtin_bit_cast(unsigned, x);
    u = (u + 0x7FFFu + ((u >> 16) & 1u)) >> 16;   // RNE
    return (unsigned short)u;
}
__device__ __forceinline__ float bf2f(unsigned short b){
    unsigned u = ((unsigned)b) << 16;
    return __builtin_bit_cast(float, u);
}
__device__ __forceinline__ f32x4 mfma16(bf16x8 a, bf16x8 b, f32x4 c){
    return __builtin_amdgcn_mfma_f32_16x16x32_bf16(a, b, c, 0, 0, 0);
}

// ---------------------------------------------------------------------------
// RoPE tables (f32 math mirroring reference)
// ---------------------------------------------------------------------------
__global__ __launch_bounds__(64) void rope_table_k(float* __restrict__ ct,
                                                   float* __restrict__ st){
    int s = blockIdx.x, j = threadIdx.x;
    float fr  = 1.0f / powf(10000.0f, (float)j * (1.0f / 64.0f));
    float ang = (float)s * fr;
    ct[s * 64 + j] = cosf(ang);
    st[s * 64 + j] = sinf(ang);
}

// ---------------------------------------------------------------------------
// X f32 -> bf16 hi + lo planes.  4 floats/thread.
// ---------------------------------------------------------------------------
__global__ __launch_bounds__(256) void prep_split(const float* __restrict__ src,
                                                  unsigned short* __restrict__ hi,
                                                  unsigned short* __restrict__ lo){
    size_t i = ((size_t)blockIdx.x * 256 + threadIdx.x) * 4;
    float4 x = *(const float4*)&src[i];
    unsigned short h0 = f2bfu(x.x), h1 = f2bfu(x.y), h2 = f2bfu(x.z), h3 = f2bfu(x.w);
    s16x4 hv; hv[0] = (short)h0; hv[1] = (short)h1; hv[2] = (short)h2; hv[3] = (short)h3;
    *(s16x4*)&hi[i] = hv;
    s16x4 lv;
    lv[0] = (short)f2bfu(x.x - bf2f(h0)); lv[1] = (short)f2bfu(x.y - bf2f(h1));
    lv[2] = (short)f2bfu(x.z - bf2f(h2)); lv[3] = (short)f2bfu(x.w - bf2f(h3));
    *(s16x4*)&lo[i] = lv;
}

// ---------------------------------------------------------------------------
// W (2048x2048, [k][n]) -> W^T bf16 planes ([n][k]), z selects the matrix.
// z=2 (V) emits hi only.
// ---------------------------------------------------------------------------
__global__ __launch_bounds__(256) void prep_wT3(
    const float* __restrict__ W0, const float* __restrict__ W1,
    const float* __restrict__ W2,
    unsigned short* __restrict__ Th0, unsigned short* __restrict__ Tl0,
    unsigned short* __restrict__ Th1, unsigned short* __restrict__ Tl1,
    unsigned short* __restrict__ Th2)
{
    const int z = blockIdx.z;
    const float* W = (z == 0) ? W0 : (z == 1) ? W1 : W2;
    unsigned short* Th = (z == 0) ? Th0 : (z == 1) ? Th1 : Th2;
    unsigned short* Tl = (z == 0) ? Tl0 : (z == 1) ? Tl1 : nullptr;

    __shared__ float T[64][65];
    const int k0 = blockIdx.x * 64, n0 = blockIdx.y * 64;
    const int tid = (int)threadIdx.x;
    #pragma unroll
    for (int it = 0; it < 16; ++it){
        int idx = tid + it * 256;
        int r = idx >> 6, c = idx & 63;
        T[c][r] = W[(size_t)(k0 + r) * 2048 + n0 + c];
    }
    __syncthreads();
    #pragma unroll
    for (int it = 0; it < 16; ++it){
        int idx = tid + it * 256;
        int n = idx >> 6, k = idx & 63;
        float v = T[n][k];
        unsigned short h = f2bfu(v);
        Th[(size_t)(n0 + n) * 2048 + k0 + k] = h;
        if (Tl) Tl[(size_t)(n0 + n) * 2048 + k0 + k] = f2bfu(v - bf2f(h));
    }
}

// ---------------------------------------------------------------------------
// Merged projection GEMM: z=0 -> Q (split), z=1 -> K (split), z=2 -> V (plain,
// transposed bf16 out).  128x128 tile, BK=32, 4 waves, reg-prefetch dbuf.
// ---------------------------------------------------------------------------
__global__ __launch_bounds__(256, 3) void gemm3(
    const unsigned short* __restrict__ Xh, const unsigned short* __restrict__ Xl,
    const unsigned short* __restrict__ Bqh, const unsigned short* __restrict__ Bql,
    const unsigned short* __restrict__ Bkh, const unsigned short* __restrict__ Bkl,
    const unsigned short* __restrict__ Bvh,
    const float* __restrict__ bq, const float* __restrict__ bk,
    const float* __restrict__ bv,
    float* __restrict__ qf, float* __restrict__ kf,
    unsigned short* __restrict__ vtbf, int zbase)
{
    const int z = zbase + (int)blockIdx.z;
    const bool split = (z < 2);
    const unsigned short* Bh = (z == 0) ? Bqh : (z == 1) ? Bkh : Bvh;
    const unsigned short* Bl = (z == 0) ? Bql : Bkl;
    const float* bias        = (z == 0) ? bq  : (z == 1) ? bk  : bv;

    const int m0  = blockIdx.x * 128;
    const int h   = blockIdx.y;                 // n0 = h*128
    const int tid = (int)threadIdx.x;
    const int l   = tid & 63, w = tid >> 6;
    const int wr  = w >> 1,  wc = w & 1;
    const int cc  = l & 15,  g  = l >> 4;

    __shared__ short As[2][128][40];
    __shared__ short Bs[2][128][40];

    f32x4 acc[4][4] = {};
    bf16x8 rah[2], ral[2], rbh[2], rbl[2];

    auto LOADSTEP = [&](int k0){
        #pragma unroll
        for (int it = 0; it < 2; ++it){
            int c = tid + it * 256;                  // 0..511
            int row = c >> 2, col8 = (c & 3) * 8;
            rah[it] = *(const bf16x8*)&Xh[(size_t)(m0 + row) * 2048 + k0 + col8];
            rbh[it] = *(const bf16x8*)&Bh[(size_t)(h * 128 + row) * 2048 + k0 + col8];
            if (split){
                ral[it] = *(const bf16x8*)&Xl[(size_t)(m0 + row) * 2048 + k0 + col8];
                rbl[it] = *(const bf16x8*)&Bl[(size_t)(h * 128 + row) * 2048 + k0 + col8];
            }
        }
    };
    auto STORESTEP = [&](){
        #pragma unroll
        for (int it = 0; it < 2; ++it){
            int c = tid + it * 256;
            int row = c >> 2, col8 = (c & 3) * 8;
            *(bf16x8*)&As[0][row][col8] = rah[it];
            *(bf16x8*)&Bs[0][row][col8] = rbh[it];
            if (split){
                *(bf16x8*)&As[1][row][col8] = ral[it];
                *(bf16x8*)&Bs[1][row][col8] = rbl[it];
            }
        }
    };

    LOADSTEP(0); STORESTEP(); __syncthreads();
    for (int k0 = 0; k0 < 2048; k0 += 32){
        bool more = (k0 + 32) < 2048;
        if (more) LOADSTEP(k0 + 32);

        bf16x8 ah[4], bh[4];
        #pragma unroll
        for (int mt = 0; mt < 4; ++mt)
            ah[mt] = *(const bf16x8*)&As[0][wr * 64 + mt * 16 + cc][g * 8];
        #pragma unroll
        for (int nt = 0; nt < 4; ++nt)
            bh[nt] = *(const bf16x8*)&Bs[0][wc * 64 + nt * 16 + cc][g * 8];
        if (split){
            bf16x8 al[4], bl[4];
            #pragma unroll
            for (int mt = 0; mt < 4; ++mt)
                al[mt] = *(const bf16x8*)&As[1][wr * 64 + mt * 16 + cc][g * 8];
            #pragma unroll
            for (int nt = 0; nt < 4; ++nt)
                bl[nt] = *(const bf16x8*)&Bs[1][wc * 64 + nt * 16 + cc][g * 8];
            #pragma unroll
            for (int mt = 0; mt < 4; ++mt)
                #pragma unroll
                for (int nt = 0; nt < 4; ++nt){
                    acc[mt][nt] = mfma16(ah[mt], bh[nt], acc[mt][nt]);
                    acc[mt][nt] = mfma16(ah[mt], bl[nt], acc[mt][nt]);
                    acc[mt][nt] = mfma16(al[mt], bh[nt], acc[mt][nt]);
                }
        } else {
            #pragma unroll
            for (int mt = 0; mt < 4; ++mt)
                #pragma unroll
                for (int nt = 0; nt < 4; ++nt)
                    acc[mt][nt] = mfma16(ah[mt], bh[nt], acc[mt][nt]);
        }
        __syncthreads();
        if (more){ STORESTEP(); __syncthreads(); }
    }

    #pragma unroll
    for (int mt = 0; mt < 4; ++mt)
        #pragma unroll
        for (int nt = 0; nt < 4; ++nt)
            #pragma unroll
            for (int j = 0; j < 4; ++j){
                int srow = m0 + wr * 64 + mt * 16 + g * 4 + j;
                int col  = wc * 64 + nt * 16 + cc;
                float v = acc[mt][nt][j] + bias[h * 128 + col];
                if (z == 0)      qf[((size_t)h * 2048 + srow) * 128 + col] = v;
                else if (z == 1) kf[((size_t)h * 2048 + srow) * 128 + col] = v;
                else             vtbf[((size_t)h * 128 + col) * 2048 + srow] = f2bfu(v);
            }
}

// ---------------------------------------------------------------------------
// In-place RoPE on qf/kf (f32) + emit bf16 copies qbb/kbb.
// ---------------------------------------------------------------------------
__global__ __launch_bounds__(256) void rope_apply(
    float* __restrict__ qf, float* __restrict__ kf,
    unsigned short* __restrict__ qbb, unsigned short* __restrict__ kbb,
    const float* __restrict__ ct, const float* __restrict__ st)
{
    int idx = blockIdx.x * 256 + (int)threadIdx.x;
    int j = idx & 63;
    int s = (idx >> 6) & 2047;
    int h = (idx >> 17) & 15;
    int a = idx >> 21;
    size_t off = ((size_t)h * 2048 + s) * 128;
    float* p = (a ? kf : qf) + off;
    unsigned short* pb = (a ? kbb : qbb) + off;
    float c = ct[s * 64 + j], sn = st[s * 64 + j];
    float x1 = p[j], x2 = p[j + 64];
    float y1 = x1 * c - x2 * sn;
    float y2 = x2 * c + x1 * sn;
    p[j]      = y1;  p[j + 64]  = y2;
    pb[j] = f2bfu(y1); pb[j + 64] = f2bfu(y2);
}

// ---------------------------------------------------------------------------
// Block means: k_cmp from roped f32 K; v_cmp from transposed bf16 V.
// ---------------------------------------------------------------------------
__global__ __launch_bounds__(256) void cmp_mean(
    const float* __restrict__ kf, const unsigned short* __restrict__ vtbf,
    float* __restrict__ kcmp, float* __restrict__ vcmp)
{
    int idx = blockIdx.x * 256 + (int)threadIdx.x;   // 16*64*128
    int d  = idx & 127;
    int nb = (idx >> 7) & 63;
    int h  = idx >> 13;
    const float* kp = &kf[((size_t)h * 2048 + nb * 32) * 128 + d];
    float sk = 0.f;
    #pragma unroll
    for (int t = 0; t < 32; ++t) sk += kp[t * 128];
    const unsigned short* vp = &vtbf[((size_t)h * 128 + d) * 2048 + nb * 32];
    float sv = 0.f;
    #pragma unroll
    for (int t = 0; t < 32; ++t) sv += bf2f(vp[t]);
    kcmp[((size_t)h * 64 + nb) * 128 + d] = sk * 0.03125f;
    vcmp[((size_t)h * 64 + nb) * 128 + d] = sv * 0.03125f;
}

// ---------------------------------------------------------------------------
// Compressed attention + top-8 selection + gates, tiled per (qtile, head).
// Phase A: f32 64x64x128 score GEMM from LDS.  Gates from staged Q.
// Phase B: per-wave softmax + shuffle top-k; PV via bf16 MFMA.
// Writes out = g0*out_cmp (base layer), gout, bmask.
// ---------------------------------------------------------------------------
__global__ __launch_bounds__(256) void cmp_attn(
    const float* __restrict__ qf, const float* __restrict__ kcmp,
    const float* __restrict__ vcmp,
    const float* __restrict__ Wg, const float* __restrict__ bg,
    float* __restrict__ out, float* __restrict__ gout,
    unsigned long long* __restrict__ bmask)
{
    const int h = blockIdx.y, qt = blockIdx.x, i0 = qt * 64;
    const int tid = (int)threadIdx.x;
    const int l = tid & 63, w = tid >> 6;
    const int ty = tid >> 4, tx = tid & 15;
    const int cc = l & 15, g = l >> 4;

    __shared__ __align__(16) char smem[65536];
    __shared__ float sgl[4][16][3];
    float4* qs4 = (float4*)smem;                                  // [64][32]
    float4* kc4 = (float4*)(smem + 32768);                        // [64][32]
    unsigned short* vcT = (unsigned short*)smem;                  // [128][72]
    float* sc = (float*)(smem + 32768);                           // [64][68]
    unsigned short* ps = (unsigned short*)(smem + 32768 + 17408); // [64][72]

    // ---- stage Q tile and k_cmp (f32, XOR-swizzled float4 chunks) ----
    #pragma unroll
    for (int it = 0; it < 8; ++it){
        int idx = tid + it * 256;            // 0..2047
        int row = idx >> 5, c = idx & 31;
        int cs = c ^ ((row >> 2) & 7);
        qs4[row * 32 + cs] = *(const float4*)&qf[((size_t)h * 2048 + i0 + row) * 128 + c * 4];
        kc4[row * 32 + cs] = *(const float4*)&kcmp[((size_t)h * 64 + row) * 128 + c * 4];
    }
    __syncthreads();

    // ---- gates for this wave's 16 queries (Q already in LDS) ----
    {
        int gi = l & 3, qq = l >> 2;         // lanes 0..63 -> 16 q x 4 (gi=3 idle)
        if (gi < 3){
            int q = w * 16 + qq;
            float acc = 0.f;
            #pragma unroll
            for (int c = 0; c < 32; ++c){
                float4 qv = qs4[q * 32 + (c ^ ((q >> 2) & 7))];
                const float* wgp = &Wg[(size_t)h * 384 + (c * 4) * 3 + gi];
                acc += qv.x * wgp[0] + qv.y * wgp[3] + qv.z * wgp[6] + qv.w * wgp[9];
            }
            float gv = 1.f / (1.f + expf(-(acc + bg[gi])));
            sgl[w][qq][gi] = gv;
            gout[((size_t)h * 2048 + i0 + q) * 3 + gi] = gv;
        }
    }

    // ---- scores: 64x64x128 f32, 4 rows x 4 cols per thread ----
    float acc[4][4] = {};
    #pragma unroll 2
    for (int k0 = 0; k0 < 32; ++k0){
        float4 qv[4], kv[4];
        #pragma unroll
        for (int j = 0; j < 4; ++j) qv[j] = qs4[(4 * ty + j) * 32 + (k0 ^ (ty & 7))];
        #pragma unroll
        for (int c = 0; c < 4; ++c) kv[c] = kc4[(4 * tx + c) * 32 + (k0 ^ (tx & 7))];
        #pragma unroll
        for (int j = 0; j < 4; ++j)
            #pragma unroll
            for (int c = 0; c < 4; ++c)
                acc[j][c] += qv[j].x * kv[c].x + qv[j].y * kv[c].y
                           + qv[j].z * kv[c].z + qv[j].w * kv[c].w;
    }
    __syncthreads();

    // ---- masked scores -> sc; stage v_cmp^T bf16 -> vcT ----
    #pragma unroll
    for (int j = 0; j < 4; ++j){
        int r = 4 * ty + j, i = i0 + r;
        float4 sv;
        float* svp = (float*)&sv;
        #pragma unroll
        for (int c = 0; c < 4; ++c){
            int b = 4 * tx + c;
            svp[c] = (b * 32 + 31 <= i) ? acc[j][c] * SCALE_F : -1e9f;
        }
        *(float4*)&sc[r * 68 + 4 * tx] = sv;
    }
    #pragma unroll
    for (int it = 0; it < 8; ++it){
        int idx = tid + it * 256;            // 0..2047
        int jb = idx >> 5, d4 = (idx & 31) * 4;
        float4 vx = *(const float4*)&vcmp[((size_t)h * 64 + jb) * 128 + d4];
        const float* vp = (const float*)&vx;
        #pragma unroll
        for (int jj = 0; jj < 4; ++jj)
            vcT[(d4 + jj) * 72 + jb] = f2bfu(vp[jj]);
    }
    __syncthreads();

    // ---- per-wave softmax + top-8 (16 queries per wave) ----
    for (int qq = 0; qq < 16; ++qq){
        const int q = w * 16 + qq;
        float s = sc[q * 68 + l];
        float mx = s;
        #pragma unroll
        for (int off = 1; off < 64; off <<= 1) mx = fmaxf(mx, __shfl_xor(mx, off));
        float p = expf(s - mx);
        float sum = p;
        #pragma unroll
        for (int off = 1; off < 64; off <<= 1) sum += __shfl_xor(sum, off);
        p /= sum;
        ps[q * 72 + l] = f2bfu(p);

        unsigned long long sel = 1ULL << ((i0 + q) >> 5);
        unsigned long long key = (1ULL << 45) |
            ((unsigned long long)__builtin_bit_cast(unsigned, p) << 7) |
            (unsigned long long)(63 - l);
        #pragma unroll
        for (int it = 0; it < 8; ++it){
            unsigned long long k2 = key;
            #pragma unroll
            for (int off = 1; off < 64; off <<= 1){
                unsigned long long o = __shfl_xor(k2, off);
                k2 = (o > k2) ? o : k2;
            }
            int wb = 63 - (int)(k2 & 63ULL);
            sel |= 1ULL << wb;
            if (l == wb) key = 0ULL;
        }
        if (l == 0) bmask[(size_t)h * 2048 + i0 + q] = sel;
    }
    __syncthreads();

    // ---- PV via bf16 MFMA; write base layer g0*out_cmp ----
    f32x4 oacc[8] = {};
    #pragma unroll
    for (int kk = 0; kk < 2; ++kk){
        bf16x8 pa = *(const bf16x8*)&ps[(w * 16 + cc) * 72 + kk * 32 + g * 8];
        #pragma unroll
        for (int nt2 = 0; nt2 < 8; ++nt2){
            bf16x8 vfr = *(const bf16x8*)&vcT[(nt2 * 16 + cc) * 72 + kk * 32 + g * 8];
            oacc[nt2] = mfma16(pa, vfr, oacc[nt2]);
        }
    }
    #pragma unroll
    for (int j = 0; j < 4; ++j){
        int q = w * 16 + g * 4 + j, iq = i0 + q;
        float g0 = sgl[w][g * 4 + j][0];
        float f = (iq >= 31) ? g0 : 0.f;
        #pragma unroll
        for (int nt2 = 0; nt2 < 8; ++nt2)
            out[(size_t)iq * 2048 + h * 128 + nt2 * 16 + cc] = f * oacc[nt2][j];
    }
}

// ---------------------------------------------------------------------------
// Merged sparse attention: blockIdx.x<32 -> sel branch (qt=31-x, heavy first);
// else win branch (qt=63-x).  4 waves, reg-staged KV prefetch, XOR-swizzled
// LDS, defer-max online softmax (exp2 domain), per-lane deferred l-sum,
// 2 barriers/iter.  atomicAdd(g*O/l) into out.
// ---------------------------------------------------------------------------
__global__ __launch_bounds__(256, 3) void attn_ws(
    const unsigned short* __restrict__ qbf,   // [h][s][128] bf16
    const unsigned short* __restrict__ kbf,   // [h][s][128] bf16
    const unsigned short* __restrict__ vtbf,  // [h][128][2048] bf16 (V^T)
    const float* __restrict__ gates,          // [h][s][3]
    const unsigned long long* __restrict__ bmask,
    float* __restrict__ out)                  // [s][2048], atomic accumulate
{
    const int h  = blockIdx.y;
    const bool SEL = ((int)blockIdx.x < 32);
    const int qt = SEL ? 31 - (int)blockIdx.x : 63 - (int)blockIdx.x;
    const int i0 = qt * 64;
    const int tid = (int)threadIdx.x;
    const int l = tid & 63, w = tid >> 6;
    const int cc = l & 15,  g = l >> 4;

    __shared__ short Ks[64 * 128];    // [tok][d8^swz]
    __shared__ short Vt[128 * 64];    // [d][tok8^swz]
    __shared__ short Ps[4][16 * 64];  // [wave][row][col^swz]

    unsigned long long um = 0;
    if (SEL){
        um = bmask[(size_t)h * 2048 + i0 + l];
        #pragma unroll
        for (int off = 1; off < 64; off <<= 1) um |= __shfl_xor(um, off);
    }

    unsigned long long bm[4];
    int mrow[4];
    #pragma unroll
    for (int j = 0; j < 4; ++j){
        mrow[j] = i0 + w * 16 + g * 4 + j;
        bm[j] = SEL ? bmask[(size_t)h * 2048 + mrow[j]] : 0ULL;
    }

    bf16x8 qfrag[4];
    {
        const unsigned short* qrow = &qbf[((size_t)h * 2048 + i0 + w * 16 + cc) * 128];
        #pragma unroll
        for (int kk = 0; kk < 4; ++kk)
            qfrag[kk] = *(const bf16x8*)&qrow[kk * 32 + g * 8];
    }

    f32x4 oacc[8] = {};
    float mrun[4], lsum[4];
    #pragma unroll
    for (int j = 0; j < 4; ++j){ mrun[j] = -1e30f; lsum[j] = 0.f; }

    const int chlo = SEL ? 0 : (qt > 8 ? qt - 8 : 0);
    auto needed = [&](int ch)->bool {
        return SEL ? (((um >> (2 * ch)) & 3ULL) != 0ULL) : true;
    };

    bf16x8 rk[4], rv[4];
    auto LOADC = [&](int ch){
        #pragma unroll
        for (int it = 0; it < 4; ++it){
            int c = tid + it * 256;   // 0..1023
            int tok = c >> 4, d8 = c & 15;
            rk[it] = *(const bf16x8*)&kbf[((size_t)h * 2048 + ch * 64 + tok) * 128 + d8 * 8];
            int vd = c >> 3, t8 = c & 7;
            rv[it] = *(const bf16x8*)&vtbf[((size_t)h * 128 + vd) * 2048 + ch * 64 + t8 * 8];
        }
    };
    auto STOREC = [&](){
        #pragma unroll
        for (int it = 0; it < 4; ++it){
            int c = tid + it * 256;
            int tok = c >> 4, d8 = c & 15;
            *(bf16x8*)&Ks[tok * 128 + ((d8 ^ (tok & 7)) << 3)] = rk[it];
            int vd = c >> 3, t8 = c & 7;
            *(bf16x8*)&Vt[vd * 64 + ((t8 ^ (vd & 7)) << 3)] = rv[it];
        }
    };

    int cur = chlo;
    while (cur <= qt && !needed(cur)) ++cur;   // chunk qt always needed
    LOADC(cur); STOREC(); __syncthreads();

    while (cur <= qt){
        int nxt = cur + 1;
        while (nxt <= qt && !needed(nxt)) ++nxt;
        const bool more = (nxt <= qt);
        if (more) LOADC(nxt);

        // ---- QK^T ----
        f32x4 sacc[4] = {};
        #pragma unroll
        for (int kk = 0; kk < 4; ++kk)
            #pragma unroll
            for (int nt = 0; nt < 4; ++nt){
                bf16x8 kfr = *(const bf16x8*)
                    &Ks[(nt * 16 + cc) * 128 + (((kk * 4 + g) ^ (cc & 7)) << 3)];
                sacc[nt] = mfma16(qfrag[kk], kfr, sacc[nt]);
            }

        // ---- defer-max online softmax (exp2 domain) ----
        const int tbase = cur * 64;
        #pragma unroll
        for (int j = 0; j < 4; ++j){
            const int iq = mrow[j];
            const int row = g * 4 + j;
            float sj[4]; bool ok[4];
            float mx = -1e30f;
            #pragma unroll
            for (int nt = 0; nt < 4; ++nt){
                int t = tbase + nt * 16 + cc;
                bool o = (t <= iq) &&
                         (SEL ? (((bm[j] >> (t >> 5)) & 1ULL) != 0ULL)
                              : ((iq - t) < 512));
                float s = sacc[nt][j] * SCL2E;
                sj[nt] = s; ok[nt] = o;
                if (o) mx = fmaxf(mx, s);
            }
            #pragma unroll
            for (int off = 1; off < 16; off <<= 1)
                mx = fmaxf(mx, __shfl_xor(mx, off));
            float mo = mrun[j];
            if (mx > mo + 8.f){                 // group-uniform rescale (rare)
                float al = exp2f(mo - mx);
                mrun[j] = mo = mx;
                lsum[j] *= al;
                #pragma unroll
                for (int nt2 = 0; nt2 < 8; ++nt2) oacc[nt2][j] *= al;
            }
            float pacc = 0.f;
            #pragma unroll
            for (int nt = 0; nt < 4; ++nt){
                float p = ok[nt] ? exp2f(sj[nt] - mo) : 0.f;
                pacc += p;
                Ps[w][row * 64 + ((nt * 16 + cc) ^ ((row & 7) << 3))] = (short)f2bfu(p);
            }
            lsum[j] += pacc;
        }

        // ---- PV (Ps is wave-private: no barrier needed) ----
        #pragma unroll
        for (int kk = 0; kk < 2; ++kk){
            bf16x8 pa = *(const bf16x8*)
                &Ps[w][cc * 64 + (((kk * 4 + g) ^ (cc & 7)) << 3)];
            #pragma unroll
            for (int nt2 = 0; nt2 < 8; ++nt2){
                int vd = nt2 * 16 + cc;
                bf16x8 vfr = *(const bf16x8*)
                    &Vt[vd * 64 + (((kk * 4 + g) ^ (cc & 7)) << 3)];
                oacc[nt2] = mfma16(pa, vfr, oacc[nt2]);
            }
        }
        __syncthreads();                // all waves done reading Ks/Vt
        if (more){ STOREC(); __syncthreads(); }
        cur = more ? nxt : qt + 1;
    }

    // ---- epilogue: reduce l over 16 lanes, atomic out += g * O / l ----
    const int GI = SEL ? 1 : 2;
    #pragma unroll
    for (int j = 0; j < 4; ++j){
        float ls = lsum[j];
        #pragma unroll
        for (int off = 1; off < 16; off <<= 1) ls += __shfl_xor(ls, off);
        const int iq = mrow[j];
        float gv  = gates[((size_t)h * 2048 + iq) * 3 + GI];
        float inv = gv / ls;
        #pragma unroll
        for (int nt2 = 0; nt2 < 8; ++nt2){
            int d = nt2 * 16 + cc;
            atomicAdd(&out[(size_t)iq * 2048 + h * 128 + d], oacc[nt2][j] * inv);
        }
    }
}

// ---------------------------------------------------------------------------
extern "C" void kernel_launch(void* const* d_in, const int* in_sizes, int n_in,
                              void* d_out, int out_size, void* d_ws, size_t ws_size,
                              hipStream_t stream)
{
    const float* X  = (const float*)d_in[0];
    const float* Wq = (const float*)d_in[1];
    const float* bq = (const float*)d_in[2];
    const float* Wk = (const float*)d_in[3];
    const float* bk = (const float*)d_in[4];
    const float* Wv = (const float*)d_in[5];
    const float* bv = (const float*)d_in[6];
    const float* Wg = (const float*)d_in[7];
    const float* bg = (const float*)d_in[8];
    float* out = (float*)d_out;

    const size_t MBs = (size_t)1 << 20;
    char* ws = (char*)d_ws;
    const bool bigws = ws_size >= 100 * MBs;

    unsigned short *Xh, *Xl, *WQH, *WQL, *WKH, *WKL, *WVH;
    float *qf, *kf;
    unsigned short *vtbf, *qbf, *kbf;
    size_t SM;
    if (bigws){
        Xh  = (unsigned short*)(ws + 0 * MBs);
        Xl  = (unsigned short*)(ws + 8 * MBs);
        WQH = (unsigned short*)(ws + 16 * MBs);
        WQL = (unsigned short*)(ws + 24 * MBs);
        WKH = (unsigned short*)(ws + 32 * MBs);
        WKL = (unsigned short*)(ws + 40 * MBs);
        WVH = (unsigned short*)(ws + 48 * MBs);
        qf  = (float*)(ws + 56 * MBs);
        kf  = (float*)(ws + 72 * MBs);
        vtbf = (unsigned short*)(ws + 88 * MBs);
        qbf = WQH; kbf = WQL;               // W dead after gemm3
        SM  = 96 * MBs;
    } else {
        Xh  = (unsigned short*)(ws + 0 * MBs);
        Xl  = (unsigned short*)(ws + 8 * MBs);
        WQH = WKH = WVH = (unsigned short*)(ws + 16 * MBs);   // shared WT
        WQL = WKL       = (unsigned short*)(ws + 24 * MBs);
        qf  = (float*)(ws + 32 * MBs);
        kf  = (float*)(ws + 48 * MBs);
        vtbf = (unsigned short*)(ws + 64 * MBs);
        qbf = (unsigned short*)(ws + 16 * MBs);
        kbf = (unsigned short*)(ws + 24 * MBs);
        SM  = 72 * MBs;
    }
    float* cost  = (float*)(ws + SM);
    float* sint  = (float*)(ws + SM + 524288);
    float* kcmp  = (float*)(ws + SM + 1048576);
    float* vcmp  = (float*)(ws + SM + 1572864);
    float* gatesb = (float*)(ws + SM + 2097152);
    unsigned long long* bmaskb = (unsigned long long*)(ws + SM + 2097152 + 393216);

    rope_table_k<<<2048, 64, 0, stream>>>(cost, sint);
    prep_split<<<4096, 256, 0, stream>>>(X, Xh, Xl);

    if (bigws){
        prep_wT3<<<dim3(32, 32, 3), 256, 0, stream>>>(Wq, Wk, Wv,
                                                      WQH, WQL, WKH, WKL, WVH);
        gemm3<<<dim3(16, 16, 3), 256, 0, stream>>>(Xh, Xl, WQH, WQL, WKH, WKL,
                                                   WVH, bq, bk, bv, qf, kf, vtbf, 0);
    } else {
        prep_wT3<<<dim3(32, 32, 1), 256, 0, stream>>>(Wq, nullptr, nullptr,
                                                      WQH, WQL, nullptr, nullptr, nullptr);
        gemm3<<<dim3(16, 16, 1), 256, 0, stream>>>(Xh, Xl, WQH, WQL, WKH, WKL,
                                                   WVH, bq, bk, bv, qf, kf, vtbf, 0);
        prep_wT3<<<dim3(32, 32, 1), 256, 0, stream>>>(Wk, nullptr, nullptr,
                                                      WKH, WKL, nullptr, nullptr, nullptr);
        gemm3<<<dim3(16, 16, 1), 256, 0, stream>>>(Xh, Xl, WQH, WQL, WKH, WKL,
                                                   WVH, bq, bk, bv, qf, kf, vtbf, 1);
        prep_wT3<<<dim3(32, 32, 1), 256, 0, stream>>>(Wv, nullptr, nullptr,
                                                      WVH, nullptr, nullptr, nullptr, nullptr);
        gemm3<<<dim3(16, 16, 1), 256, 0, stream>>>(Xh, Xl, WQH, WQL, WKH, WKL,
                                                   WVH, bq, bk, bv, qf, kf, vtbf, 2);
    }

    rope_apply<<<16384, 256, 0, stream>>>(qf, kf, qbf, kbf, cost, sint);
    cmp_mean<<<512, 256, 0, stream>>>(kf, vtbf, kcmp, vcmp);
    cmp_attn<<<dim3(32, 16), 256, 0, stream>>>(qf, kcmp, vcmp, Wg, bg,
                                               out, gatesb, bmaskb);
    attn_ws<<<dim3(64, 16), 256, 0, stream>>>(qbf, kbf, vtbf, gatesb, bmaskb, out);
}

// Round 5
// 667.567 us; speedup vs baseline: 1.9338x; 1.9338x over previous
//
#include <hip/hip_runtime.h>

// ---------------------------------------------------------------------------
// NSA attention forward, B=1, S=2048, HID=2048, H=16, D=128, L=32, NB=64,
// NSEL=8, WIN=512.  f32 in/out.  bf16 MFMA compute (split hi/lo bf16 for the
// selection-critical Q/K projections; f32 VALU for selection-critical cmp
// scores).  Round 5: round-3 structure + (a) XCD-rectangle GEMM swizzle,
// (b) merged win+sel attention with round-3 internals + atomicAdd epilogue,
// (c) gates fused into cmp_attn, bf16 q/k emitted by rope_apply.
// ---------------------------------------------------------------------------

#define SCALE_F 0.08838834764831845f                         // 1/sqrt(128)
#define SCL2E   (0.08838834764831845f * 1.4426950408889634f) // SCALE*log2(e)

typedef short  bf16x8 __attribute__((ext_vector_type(8)));
typedef short  s16x4  __attribute__((ext_vector_type(4)));
typedef float  f32x4  __attribute__((ext_vector_type(4)));

__device__ __forceinline__ unsigned short f2bfu(float x){
    unsigned u = __builtin_bit_cast(unsigned, x);
    u = (u + 0x7FFFu + ((u >> 16) & 1u)) >> 16;   // RNE
    return (unsigned short)u;
}
__device__ __forceinline__ float bf2f(unsigned short b){
    unsigned u = ((unsigned)b) << 16;
    return __builtin_bit_cast(float, u);
}
__device__ __forceinline__ f32x4 mfma16(bf16x8 a, bf16x8 b, f32x4 c){
    return __builtin_amdgcn_mfma_f32_16x16x32_bf16(a, b, c, 0, 0, 0);
}

// ---------------------------------------------------------------------------
// RoPE tables (f32 math mirroring reference)
// ---------------------------------------------------------------------------
__global__ __launch_bounds__(64) void rope_table_k(float* __restrict__ ct,
                                                   float* __restrict__ st){
    int s = blockIdx.x, j = threadIdx.x;
    float fr  = 1.0f / powf(10000.0f, (float)j * (1.0f / 64.0f));
    float ang = (float)s * fr;
    ct[s * 64 + j] = cosf(ang);
    st[s * 64 + j] = sinf(ang);
}

// ---------------------------------------------------------------------------
// X f32 -> bf16 hi + lo planes.  4 floats/thread.
// ---------------------------------------------------------------------------
__global__ __launch_bounds__(256) void prep_split(const float* __restrict__ src,
                                                  unsigned short* __restrict__ hi,
                                                  unsigned short* __restrict__ lo){
    size_t i = ((size_t)blockIdx.x * 256 + threadIdx.x) * 4;
    float4 x = *(const float4*)&src[i];
    unsigned short h0 = f2bfu(x.x), h1 = f2bfu(x.y), h2 = f2bfu(x.z), h3 = f2bfu(x.w);
    s16x4 hv; hv[0] = (short)h0; hv[1] = (short)h1; hv[2] = (short)h2; hv[3] = (short)h3;
    *(s16x4*)&hi[i] = hv;
    s16x4 lv;
    lv[0] = (short)f2bfu(x.x - bf2f(h0)); lv[1] = (short)f2bfu(x.y - bf2f(h1));
    lv[2] = (short)f2bfu(x.z - bf2f(h2)); lv[3] = (short)f2bfu(x.w - bf2f(h3));
    *(s16x4*)&lo[i] = lv;
}

// ---------------------------------------------------------------------------
// W (2048x2048, [k][n]) -> W^T bf16 planes ([n][k]), hi + optional lo.
// ---------------------------------------------------------------------------
__global__ __launch_bounds__(256) void prep_wT(const float* __restrict__ W,
                                               unsigned short* __restrict__ Th,
                                               unsigned short* __restrict__ Tl){
    __shared__ float T[64][65];
    const int k0 = blockIdx.x * 64, n0 = blockIdx.y * 64;
    const int tid = (int)threadIdx.x;
    #pragma unroll
    for (int it = 0; it < 16; ++it){
        int idx = tid + it * 256;
        int r = idx >> 6, c = idx & 63;
        T[c][r] = W[(size_t)(k0 + r) * 2048 + n0 + c];
    }
    __syncthreads();
    #pragma unroll
    for (int it = 0; it < 16; ++it){
        int idx = tid + it * 256;
        int n = idx >> 6, k = idx & 63;
        float v = T[n][k];
        unsigned short h = f2bfu(v);
        Th[(size_t)(n0 + n) * 2048 + k0 + k] = h;
        if (Tl) Tl[(size_t)(n0 + n) * 2048 + k0 + k] = f2bfu(v - bf2f(h));
    }
}

// ---------------------------------------------------------------------------
// GEMM from pre-converted bf16 planes.  C = A @ B^T_planes + bias.
// 128x128 tile, BK=32, 4 waves, reg-prefetch double-buffering.
// 1-D grid of 256 blocks; XCD-rectangle swizzle: each XCD owns a 4m x 8h
// rectangle so its L2 holds a small, shared set of K-slices.
// ---------------------------------------------------------------------------
template <int P>
__global__ __launch_bounds__(256) void gemm_bf(
    const unsigned short* __restrict__ Ah, const unsigned short* __restrict__ Al,
    const unsigned short* __restrict__ Bh, const unsigned short* __restrict__ Bl,
    const float* __restrict__ bias,
    float* __restrict__ outF, unsigned short* __restrict__ outT)
{
    const unsigned short* Ap[2] = {Ah, Al};
    const unsigned short* Bp[2] = {Bh, Bl};

    const int bid = (int)blockIdx.x;             // 0..255
    const int xcd = bid & 7, idx = bid >> 3;     // blocks round-robin XCDs
    const int m0  = (((xcd >> 1) << 2) + (idx & 3)) * 128;   // 4 m-tiles/XCD
    const int h   = ((xcd & 1) << 3) + (idx >> 2);           // 8 h-tiles/XCD

    const int tid = (int)threadIdx.x;
    const int l   = tid & 63, w = tid >> 6;
    const int wr  = w >> 1,  wc = w & 1;
    const int cc  = l & 15,  g  = l >> 4;

    __shared__ short As[P][128][40];
    __shared__ short Bs[P][128][40];

    f32x4 acc[4][4] = {};
    bf16x8 ra[P][2], rb[P][2];

    auto LOADSTEP = [&](int k0){
        #pragma unroll
        for (int p = 0; p < P; ++p)
            #pragma unroll
            for (int it = 0; it < 2; ++it){
                int c = tid + it * 256;                  // 0..511
                int row = c >> 2, col8 = (c & 3) * 8;
                ra[p][it] = *(const bf16x8*)&Ap[p][(size_t)(m0 + row) * 2048 + k0 + col8];
                rb[p][it] = *(const bf16x8*)&Bp[p][(size_t)(h * 128 + row) * 2048 + k0 + col8];
            }
    };
    auto STORESTEP = [&](){
        #pragma unroll
        for (int p = 0; p < P; ++p)
            #pragma unroll
            for (int it = 0; it < 2; ++it){
                int c = tid + it * 256;
                int row = c >> 2, col8 = (c & 3) * 8;
                *(bf16x8*)&As[p][row][col8] = ra[p][it];
                *(bf16x8*)&Bs[p][row][col8] = rb[p][it];
            }
    };

    LOADSTEP(0); STORESTEP(); __syncthreads();
    for (int k0 = 0; k0 < 2048; k0 += 32){
        bool more = (k0 + 32) < 2048;
        if (more) LOADSTEP(k0 + 32);

        bf16x8 ah[4], bh[4];
        #pragma unroll
        for (int mt = 0; mt < 4; ++mt)
            ah[mt] = *(const bf16x8*)&As[0][wr * 64 + mt * 16 + cc][g * 8];
        #pragma unroll
        for (int nt = 0; nt < 4; ++nt)
            bh[nt] = *(const bf16x8*)&Bs[0][wc * 64 + nt * 16 + cc][g * 8];
        if (P == 2){
            bf16x8 al[4], bl[4];
            #pragma unroll
            for (int mt = 0; mt < 4; ++mt)
                al[mt] = *(const bf16x8*)&As[P - 1][wr * 64 + mt * 16 + cc][g * 8];
            #pragma unroll
            for (int nt = 0; nt < 4; ++nt)
                bl[nt] = *(const bf16x8*)&Bs[P - 1][wc * 64 + nt * 16 + cc][g * 8];
            #pragma unroll
            for (int mt = 0; mt < 4; ++mt)
                #pragma unroll
                for (int nt = 0; nt < 4; ++nt){
                    acc[mt][nt] = mfma16(ah[mt], bh[nt], acc[mt][nt]);
                    acc[mt][nt] = mfma16(ah[mt], bl[nt], acc[mt][nt]);
                    acc[mt][nt] = mfma16(al[mt], bh[nt], acc[mt][nt]);
                }
        } else {
            #pragma unroll
            for (int mt = 0; mt < 4; ++mt)
                #pragma unroll
                for (int nt = 0; nt < 4; ++nt)
                    acc[mt][nt] = mfma16(ah[mt], bh[nt], acc[mt][nt]);
        }
        __syncthreads();
        if (more){ STORESTEP(); __syncthreads(); }
    }

    #pragma unroll
    for (int mt = 0; mt < 4; ++mt)
        #pragma unroll
        for (int nt = 0; nt < 4; ++nt)
            #pragma unroll
            for (int j = 0; j < 4; ++j){
                int srow = m0 + wr * 64 + mt * 16 + g * 4 + j;
                int col  = wc * 64 + nt * 16 + cc;
                float v = acc[mt][nt][j] + bias[h * 128 + col];
                if (outF) outF[((size_t)h * 2048 + srow) * 128 + col] = v;
                else      outT[((size_t)h * 128 + col) * 2048 + srow] = f2bfu(v);
            }
}

// ---------------------------------------------------------------------------
// In-place RoPE on qf/kf (f32) + emit bf16 copies qbb/kbb.
// ---------------------------------------------------------------------------
__global__ __launch_bounds__(256) void rope_apply(
    float* __restrict__ qf, float* __restrict__ kf,
    unsigned short* __restrict__ qbb, unsigned short* __restrict__ kbb,
    const float* __restrict__ ct, const float* __restrict__ st)
{
    int idx = blockIdx.x * 256 + (int)threadIdx.x;
    int j = idx & 63;
    int s = (idx >> 6) & 2047;
    int h = (idx >> 17) & 15;
    int a = idx >> 21;
    size_t off = ((size_t)h * 2048 + s) * 128;
    float* p = (a ? kf : qf) + off;
    unsigned short* pb = (a ? kbb : qbb) + off;
    float c = ct[s * 64 + j], sn = st[s * 64 + j];
    float x1 = p[j], x2 = p[j + 64];
    float y1 = x1 * c - x2 * sn;
    float y2 = x2 * c + x1 * sn;
    p[j]      = y1;  p[j + 64]  = y2;
    pb[j] = f2bfu(y1); pb[j + 64] = f2bfu(y2);
}

// ---------------------------------------------------------------------------
// Block means: k_cmp from roped f32 K; v_cmp from transposed bf16 V.
// ---------------------------------------------------------------------------
__global__ __launch_bounds__(256) void cmp_mean(
    const float* __restrict__ kf, const unsigned short* __restrict__ vtbf,
    float* __restrict__ kcmp, float* __restrict__ vcmp)
{
    int idx = blockIdx.x * 256 + (int)threadIdx.x;   // 16*64*128
    int d  = idx & 127;
    int nb = (idx >> 7) & 63;
    int h  = idx >> 13;
    const float* kp = &kf[((size_t)h * 2048 + nb * 32) * 128 + d];
    float sk = 0.f;
    #pragma unroll
    for (int t = 0; t < 32; ++t) sk += kp[t * 128];
    const unsigned short* vp = &vtbf[((size_t)h * 128 + d) * 2048 + nb * 32];
    float sv = 0.f;
    #pragma unroll
    for (int t = 0; t < 32; ++t) sv += bf2f(vp[t]);
    kcmp[((size_t)h * 64 + nb) * 128 + d] = sk * 0.03125f;
    vcmp[((size_t)h * 64 + nb) * 128 + d] = sv * 0.03125f;
}

// ---------------------------------------------------------------------------
// Compressed attention + top-8 selection + gates, tiled per (qtile, head).
// Phase A: f32 64x64x128 score GEMM from LDS.  Gates from staged Q.
// Phase B: per-wave softmax + shuffle top-k; PV via bf16 MFMA.
// Writes out = g0*out_cmp (base layer), gout, bmask.
// ---------------------------------------------------------------------------
__global__ __launch_bounds__(256) void cmp_attn(
    const float* __restrict__ qf, const float* __restrict__ kcmp,
    const float* __restrict__ vcmp,
    const float* __restrict__ Wg, const float* __restrict__ bg,
    float* __restrict__ out, float* __restrict__ gout,
    unsigned long long* __restrict__ bmask)
{
    const int h = blockIdx.y, qt = blockIdx.x, i0 = qt * 64;
    const int tid = (int)threadIdx.x;
    const int l = tid & 63, w = tid >> 6;
    const int ty = tid >> 4, tx = tid & 15;
    const int cc = l & 15, g = l >> 4;

    __shared__ __align__(16) char smem[65536];
    __shared__ float sgl[4][16][3];
    float4* qs4 = (float4*)smem;                                  // [64][32]
    float4* kc4 = (float4*)(smem + 32768);                        // [64][32]
    unsigned short* vcT = (unsigned short*)smem;                  // [128][72]
    float* sc = (float*)(smem + 32768);                           // [64][68]
    unsigned short* ps = (unsigned short*)(smem + 32768 + 17408); // [64][72]

    // ---- stage Q tile and k_cmp (f32, XOR-swizzled float4 chunks) ----
    #pragma unroll
    for (int it = 0; it < 8; ++it){
        int idx = tid + it * 256;            // 0..2047
        int row = idx >> 5, c = idx & 31;
        int cs = c ^ ((row >> 2) & 7);
        qs4[row * 32 + cs] = *(const float4*)&qf[((size_t)h * 2048 + i0 + row) * 128 + c * 4];
        kc4[row * 32 + cs] = *(const float4*)&kcmp[((size_t)h * 64 + row) * 128 + c * 4];
    }
    __syncthreads();

    // ---- gates for this wave's 16 queries (Q already in LDS) ----
    {
        int gi = l & 3, qq = l >> 2;         // 16 q x 4 lanes (gi=3 idle)
        if (gi < 3){
            int q = w * 16 + qq;
            float acc = 0.f;
            #pragma unroll
            for (int c = 0; c < 32; ++c){
                float4 qv = qs4[q * 32 + (c ^ ((q >> 2) & 7))];
                const float* wgp = &Wg[(size_t)h * 384 + (c * 4) * 3 + gi];
                acc += qv.x * wgp[0] + qv.y * wgp[3] + qv.z * wgp[6] + qv.w * wgp[9];
            }
            float gv = 1.f / (1.f + expf(-(acc + bg[gi])));
            sgl[w][qq][gi] = gv;
            gout[((size_t)h * 2048 + i0 + q) * 3 + gi] = gv;
        }
    }

    // ---- scores: 64x64x128 f32, 4 rows x 4 cols per thread ----
    float acc[4][4] = {};
    #pragma unroll 2
    for (int k0 = 0; k0 < 32; ++k0){
        float4 qv[4], kv[4];
        #pragma unroll
        for (int j = 0; j < 4; ++j) qv[j] = qs4[(4 * ty + j) * 32 + (k0 ^ (ty & 7))];
        #pragma unroll
        for (int c = 0; c < 4; ++c) kv[c] = kc4[(4 * tx + c) * 32 + (k0 ^ (tx & 7))];
        #pragma unroll
        for (int j = 0; j < 4; ++j)
            #pragma unroll
            for (int c = 0; c < 4; ++c)
                acc[j][c] += qv[j].x * kv[c].x + qv[j].y * kv[c].y
                           + qv[j].z * kv[c].z + qv[j].w * kv[c].w;
    }
    __syncthreads();

    // ---- masked scores -> sc; stage v_cmp^T bf16 -> vcT ----
    #pragma unroll
    for (int j = 0; j < 4; ++j){
        int r = 4 * ty + j, i = i0 + r;
        float4 sv;
        float* svp = (float*)&sv;
        #pragma unroll
        for (int c = 0; c < 4; ++c){
            int b = 4 * tx + c;
            svp[c] = (b * 32 + 31 <= i) ? acc[j][c] * SCALE_F : -1e9f;
        }
        *(float4*)&sc[r * 68 + 4 * tx] = sv;
    }
    #pragma unroll
    for (int it = 0; it < 8; ++it){
        int idx = tid + it * 256;            // 0..2047
        int jb = idx >> 5, d4 = (idx & 31) * 4;
        float4 vx = *(const float4*)&vcmp[((size_t)h * 64 + jb) * 128 + d4];
        const float* vp = (const float*)&vx;
        #pragma unroll
        for (int jj = 0; jj < 4; ++jj)
            vcT[(d4 + jj) * 72 + jb] = f2bfu(vp[jj]);
    }
    __syncthreads();

    // ---- per-wave softmax + top-8 (16 queries per wave) ----
    for (int qq = 0; qq < 16; ++qq){
        const int q = w * 16 + qq;
        float s = sc[q * 68 + l];
        float mx = s;
        #pragma unroll
        for (int off = 1; off < 64; off <<= 1) mx = fmaxf(mx, __shfl_xor(mx, off));
        float p = expf(s - mx);
        float sum = p;
        #pragma unroll
        for (int off = 1; off < 64; off <<= 1) sum += __shfl_xor(sum, off);
        p /= sum;
        ps[q * 72 + l] = f2bfu(p);

        unsigned long long sel = 1ULL << ((i0 + q) >> 5);
        unsigned long long key = (1ULL << 45) |
            ((unsigned long long)__builtin_bit_cast(unsigned, p) << 7) |
            (unsigned long long)(63 - l);
        #pragma unroll
        for (int it = 0; it < 8; ++it){
            unsigned long long k2 = key;
            #pragma unroll
            for (int off = 1; off < 64; off <<= 1){
                unsigned long long o = __shfl_xor(k2, off);
                k2 = (o > k2) ? o : k2;
            }
            int wb = 63 - (int)(k2 & 63ULL);
            sel |= 1ULL << wb;
            if (l == wb) key = 0ULL;
        }
        if (l == 0) bmask[(size_t)h * 2048 + i0 + q] = sel;
    }
    __syncthreads();

    // ---- PV via bf16 MFMA; write base layer g0*out_cmp ----
    f32x4 oacc[8] = {};
    #pragma unroll
    for (int kk = 0; kk < 2; ++kk){
        bf16x8 pa = *(const bf16x8*)&ps[(w * 16 + cc) * 72 + kk * 32 + g * 8];
        #pragma unroll
        for (int nt2 = 0; nt2 < 8; ++nt2){
            bf16x8 vfr = *(const bf16x8*)&vcT[(nt2 * 16 + cc) * 72 + kk * 32 + g * 8];
            oacc[nt2] = mfma16(pa, vfr, oacc[nt2]);
        }
    }
    #pragma unroll
    for (int j = 0; j < 4; ++j){
        int q = w * 16 + g * 4 + j, iq = i0 + q;
        float g0 = sgl[w][g * 4 + j][0];
        float f = (iq >= 31) ? g0 : 0.f;
        #pragma unroll
        for (int nt2 = 0; nt2 < 8; ++nt2)
            out[(size_t)iq * 2048 + h * 128 + nt2 * 16 + cc] = f * oacc[nt2][j];
    }
}

// ---------------------------------------------------------------------------
// Merged sparse attention, round-3 internals: blockIdx.x<32 -> sel branch
// (qt=31-x, heavy first); else win branch (qt=63-x, heavy first).  4 waves,
// reg-staged KV prefetch, padded LDS, exp2 online softmax, 3 barriers/iter.
// atomicAdd(g*O/l) into out (on top of cmp_attn's base layer).
// ---------------------------------------------------------------------------
__global__ __launch_bounds__(256) void attn_ws(
    const unsigned short* __restrict__ qbf,   // [h][s][128] bf16
    const unsigned short* __restrict__ kbf,   // [h][s][128] bf16
    const unsigned short* __restrict__ vtbf,  // [h][128][2048] bf16 (V^T)
    const float* __restrict__ gates,          // [h][s][3]
    const unsigned long long* __restrict__ bmask,
    float* __restrict__ out)                  // [s][2048], atomic accumulate
{
    const int h  = blockIdx.y;
    const int bx = (int)blockIdx.x;
    const bool SEL = bx < 32;
    const int qt = SEL ? 31 - bx : 63 - bx;
    const int i0 = qt * 64;
    const int tid = (int)threadIdx.x;
    const int l = tid & 63, w = tid >> 6;
    const int cc = l & 15,  g = l >> 4;

    __shared__ short Ks[64][136];     // K chunk [tok][d], +8 pad
    __shared__ short Vt[128][72];     // V^T chunk [d][tok], +8 pad
    __shared__ short Ps[4][16][72];   // P [wave][row][tok], +8 pad

    unsigned long long um = 0;
    if (SEL){
        um = bmask[(size_t)h * 2048 + i0 + l];
        #pragma unroll
        for (int off = 1; off < 64; off <<= 1) um |= __shfl_xor(um, off);
    }

    unsigned long long bm[4];
    int mrow[4];
    #pragma unroll
    for (int j = 0; j < 4; ++j){
        mrow[j] = i0 + w * 16 + g * 4 + j;
        bm[j] = SEL ? bmask[(size_t)h * 2048 + mrow[j]] : 0ULL;
    }

    bf16x8 qfrag[4];
    {
        const unsigned short* qrow = &qbf[((size_t)h * 2048 + i0 + w * 16 + cc) * 128];
        #pragma unroll
        for (int kk = 0; kk < 4; ++kk)
            qfrag[kk] = *(const bf16x8*)&qrow[kk * 32 + g * 8];
    }

    f32x4 oacc[8] = {};
    float mrun[4], lrun[4];
    #pragma unroll
    for (int j = 0; j < 4; ++j){ mrun[j] = -1e30f; lrun[j] = 0.f; }

    const int chlo = SEL ? 0 : (qt > 8 ? qt - 8 : 0);
    auto needed = [&](int ch)->bool {
        return SEL ? (((um >> (2 * ch)) & 3ULL) != 0ULL) : true;
    };

    bf16x8 rk[4], rv[4];
    auto LOADC = [&](int ch){
        #pragma unroll
        for (int it = 0; it < 4; ++it){
            int c = tid + it * 256;
            rk[it] = *(const bf16x8*)&kbf[((size_t)h * 2048 + ch * 64 + (c >> 4)) * 128 + (c & 15) * 8];
            rv[it] = *(const bf16x8*)&vtbf[((size_t)h * 128 + (c >> 3)) * 2048 + ch * 64 + (c & 7) * 8];
        }
    };
    auto STOREC = [&](){
        #pragma unroll
        for (int it = 0; it < 4; ++it){
            int c = tid + it * 256;
            *(bf16x8*)&Ks[c >> 4][(c & 15) * 8] = rk[it];
            *(bf16x8*)&Vt[c >> 3][(c & 7) * 8] = rv[it];
        }
    };

    int cur = chlo;
    while (cur <= qt && !needed(cur)) ++cur;   // chunk qt always needed
    LOADC(cur); STOREC(); __syncthreads();

    while (cur <= qt){
        int nxt = cur + 1;
        while (nxt <= qt && !needed(nxt)) ++nxt;
        const bool more = (nxt <= qt);
        if (more) LOADC(nxt);

        // ---- QK^T ----
        f32x4 sacc[4] = {};
        #pragma unroll
        for (int kk = 0; kk < 4; ++kk)
            #pragma unroll
            for (int nt = 0; nt < 4; ++nt){
                bf16x8 kfr = *(const bf16x8*)&Ks[nt * 16 + cc][kk * 32 + g * 8];
                sacc[nt] = mfma16(qfrag[kk], kfr, sacc[nt]);
            }

        // ---- masked online softmax (exp2 domain) ----
        const int tbase = cur * 64;
        #pragma unroll
        for (int j = 0; j < 4; ++j){
            const int iq = mrow[j];
            float sj[4]; bool ok[4];
            float mx = -1e30f;
            #pragma unroll
            for (int nt = 0; nt < 4; ++nt){
                int t = tbase + nt * 16 + cc;
                bool o = (t <= iq) &&
                         (SEL ? (((bm[j] >> (t >> 5)) & 1ULL) != 0ULL)
                              : ((iq - t) < 512));
                float s = sacc[nt][j] * SCL2E;
                sj[nt] = s; ok[nt] = o;
                if (o) mx = fmaxf(mx, s);
            }
            #pragma unroll
            for (int off = 1; off < 16; off <<= 1)
                mx = fmaxf(mx, __shfl_xor(mx, off));
            float mnew = fmaxf(mrun[j], mx);
            float alpha = exp2f(mrun[j] - mnew);
            float psum = 0.f;
            #pragma unroll
            for (int nt = 0; nt < 4; ++nt){
                float p = ok[nt] ? exp2f(sj[nt] - mnew) : 0.f;
                psum += p;
                Ps[w][g * 4 + j][nt * 16 + cc] = (short)f2bfu(p);
            }
            #pragma unroll
            for (int off = 1; off < 16; off <<= 1)
                psum += __shfl_xor(psum, off);
            mrun[j] = mnew;
            lrun[j] = lrun[j] * alpha + psum;
            #pragma unroll
            for (int nt2 = 0; nt2 < 8; ++nt2) oacc[nt2][j] *= alpha;
        }
        __syncthreads();

        // ---- PV ----
        #pragma unroll
        for (int kk = 0; kk < 2; ++kk){
            bf16x8 pa = *(const bf16x8*)&Ps[w][cc][kk * 32 + g * 8];
            #pragma unroll
            for (int nt2 = 0; nt2 < 8; ++nt2){
                bf16x8 vfr = *(const bf16x8*)&Vt[nt2 * 16 + cc][kk * 32 + g * 8];
                oacc[nt2] = mfma16(pa, vfr, oacc[nt2]);
            }
        }
        __syncthreads();
        if (more){ STOREC(); __syncthreads(); }
        cur = more ? nxt : qt + 1;
    }

    // ---- epilogue: atomic out += g * O / l ----
    const int GI = SEL ? 1 : 2;
    #pragma unroll
    for (int j = 0; j < 4; ++j){
        const int iq = mrow[j];
        float gv  = gates[((size_t)h * 2048 + iq) * 3 + GI];
        float inv = gv / lrun[j];
        #pragma unroll
        for (int nt2 = 0; nt2 < 8; ++nt2){
            int d = nt2 * 16 + cc;
            atomicAdd(&out[(size_t)iq * 2048 + h * 128 + d], oacc[nt2][j] * inv);
        }
    }
}

// ---------------------------------------------------------------------------
extern "C" void kernel_launch(void* const* d_in, const int* in_sizes, int n_in,
                              void* d_out, int out_size, void* d_ws, size_t ws_size,
                              hipStream_t stream)
{
    const float* X  = (const float*)d_in[0];
    const float* Wq = (const float*)d_in[1];
    const float* bq = (const float*)d_in[2];
    const float* Wk = (const float*)d_in[3];
    const float* bk = (const float*)d_in[4];
    const float* Wv = (const float*)d_in[5];
    const float* bv = (const float*)d_in[6];
    const float* Wg = (const float*)d_in[7];
    const float* bg = (const float*)d_in[8];
    float* out = (float*)d_out;

    const size_t MBs = (size_t)1 << 20;
    char* ws = (char*)d_ws;

    unsigned short* Xh  = (unsigned short*)(ws + 0 * MBs);
    unsigned short* Xl  = (unsigned short*)(ws + 8 * MBs);
    unsigned short* WTh = (unsigned short*)(ws + 16 * MBs);
    unsigned short* WTl = (unsigned short*)(ws + 24 * MBs);
    float* qf  = (float*)(ws + 32 * MBs);
    float* kf  = (float*)(ws + 48 * MBs);
    unsigned short* vtbf = (unsigned short*)(ws + 64 * MBs);
    unsigned short* qbf  = (unsigned short*)(ws + 16 * MBs);  // alias (W dead)
    unsigned short* kbf  = (unsigned short*)(ws + 24 * MBs);  // alias
    const size_t SM = 72 * MBs;
    float* cost  = (float*)(ws + SM);
    float* sint  = (float*)(ws + SM + 524288);
    float* kcmp  = (float*)(ws + SM + 1048576);
    float* vcmp  = (float*)(ws + SM + 1572864);
    float* gatesb = (float*)(ws + SM + 2097152);
    unsigned long long* bmaskb = (unsigned long long*)(ws + SM + 2490368);

    rope_table_k<<<2048, 64, 0, stream>>>(cost, sint);
    prep_split<<<4096, 256, 0, stream>>>(X, Xh, Xl);

    prep_wT<<<dim3(32, 32), 256, 0, stream>>>(Wq, WTh, WTl);
    gemm_bf<2><<<256, 256, 0, stream>>>(Xh, Xl, WTh, WTl, bq, qf, nullptr);
    prep_wT<<<dim3(32, 32), 256, 0, stream>>>(Wk, WTh, WTl);
    gemm_bf<2><<<256, 256, 0, stream>>>(Xh, Xl, WTh, WTl, bk, kf, nullptr);
    prep_wT<<<dim3(32, 32), 256, 0, stream>>>(Wv, WTh, nullptr);
    gemm_bf<1><<<256, 256, 0, stream>>>(Xh, nullptr, WTh, nullptr, bv, nullptr, vtbf);

    rope_apply<<<16384, 256, 0, stream>>>(qf, kf, qbf, kbf, cost, sint);
    cmp_mean<<<512, 256, 0, stream>>>(kf, vtbf, kcmp, vcmp);
    cmp_attn<<<dim3(32, 16), 256, 0, stream>>>(qf, kcmp, vcmp, Wg, bg,
                                               out, gatesb, bmaskb);
    attn_ws<<<dim3(64, 16), 256, 0, stream>>>(qbf, kbf, vtbf, gatesb, bmaskb, out);
}

// Round 8
// 591.652 us; speedup vs baseline: 2.1819x; 1.1283x over previous
//
#include <hip/hip_runtime.h>

// ---------------------------------------------------------------------------
// NSA attention forward, B=1, S=2048, HID=2048, H=16, D=128, L=32, NB=64,
// NSEL=8, WIN=512.  f32 in/out.  bf16 MFMA compute (split hi/lo bf16 for the
// selection-critical Q/K projections; f32 VALU for selection-critical cmp
// scores).  Round 8 (= round 7 resubmit after infra failure): split-K
// flash-decoding attention with the window-chunk bound fixed (qt-8, 9 chunks).
// ---------------------------------------------------------------------------

#define SCALE_F 0.08838834764831845f                         // 1/sqrt(128)
#define SCL2E   (0.08838834764831845f * 1.4426950408889634f) // SCALE*log2(e)

typedef short  bf16x8 __attribute__((ext_vector_type(8)));
typedef short  s16x4  __attribute__((ext_vector_type(4)));
typedef float  f32x4  __attribute__((ext_vector_type(4)));

__device__ __forceinline__ unsigned short f2bfu(float x){
    unsigned u = __builtin_bit_cast(unsigned, x);
    u = (u + 0x7FFFu + ((u >> 16) & 1u)) >> 16;   // RNE
    return (unsigned short)u;
}
__device__ __forceinline__ float bf2f(unsigned short b){
    unsigned u = ((unsigned)b) << 16;
    return __builtin_bit_cast(float, u);
}
__device__ __forceinline__ f32x4 mfma16(bf16x8 a, bf16x8 b, f32x4 c){
    return __builtin_amdgcn_mfma_f32_16x16x32_bf16(a, b, c, 0, 0, 0);
}

// ---------------------------------------------------------------------------
// RoPE tables (f32 math mirroring reference)
// ---------------------------------------------------------------------------
__global__ __launch_bounds__(64) void rope_table_k(float* __restrict__ ct,
                                                   float* __restrict__ st){
    int s = blockIdx.x, j = threadIdx.x;
    float fr  = 1.0f / powf(10000.0f, (float)j * (1.0f / 64.0f));
    float ang = (float)s * fr;
    ct[s * 64 + j] = cosf(ang);
    st[s * 64 + j] = sinf(ang);
}

// ---------------------------------------------------------------------------
// X f32 -> bf16 hi + lo planes.  4 floats/thread.
// ---------------------------------------------------------------------------
__global__ __launch_bounds__(256) void prep_split(const float* __restrict__ src,
                                                  unsigned short* __restrict__ hi,
                                                  unsigned short* __restrict__ lo){
    size_t i = ((size_t)blockIdx.x * 256 + threadIdx.x) * 4;
    float4 x = *(const float4*)&src[i];
    unsigned short h0 = f2bfu(x.x), h1 = f2bfu(x.y), h2 = f2bfu(x.z), h3 = f2bfu(x.w);
    s16x4 hv; hv[0] = (short)h0; hv[1] = (short)h1; hv[2] = (short)h2; hv[3] = (short)h3;
    *(s16x4*)&hi[i] = hv;
    s16x4 lv;
    lv[0] = (short)f2bfu(x.x - bf2f(h0)); lv[1] = (short)f2bfu(x.y - bf2f(h1));
    lv[2] = (short)f2bfu(x.z - bf2f(h2)); lv[3] = (short)f2bfu(x.w - bf2f(h3));
    *(s16x4*)&lo[i] = lv;
}

// ---------------------------------------------------------------------------
// W (2048x2048, [k][n]) -> W^T bf16 planes ([n][k]), hi + optional lo.
// ---------------------------------------------------------------------------
__global__ __launch_bounds__(256) void prep_wT(const float* __restrict__ W,
                                               unsigned short* __restrict__ Th,
                                               unsigned short* __restrict__ Tl){
    __shared__ float T[64][65];
    const int k0 = blockIdx.x * 64, n0 = blockIdx.y * 64;
    const int tid = (int)threadIdx.x;
    #pragma unroll
    for (int it = 0; it < 16; ++it){
        int idx = tid + it * 256;
        int r = idx >> 6, c = idx & 63;
        T[c][r] = W[(size_t)(k0 + r) * 2048 + n0 + c];
    }
    __syncthreads();
    #pragma unroll
    for (int it = 0; it < 16; ++it){
        int idx = tid + it * 256;
        int n = idx >> 6, k = idx & 63;
        float v = T[n][k];
        unsigned short h = f2bfu(v);
        Th[(size_t)(n0 + n) * 2048 + k0 + k] = h;
        if (Tl) Tl[(size_t)(n0 + n) * 2048 + k0 + k] = f2bfu(v - bf2f(h));
    }
}

// ---------------------------------------------------------------------------
// GEMM from pre-converted bf16 planes.  C = A @ B^T_planes + bias.
// 128x128 tile, BK=32, 4 waves, reg-prefetch double-buffering, XCD-rect
// swizzle (each XCD owns a 4m x 8h rectangle).
// ---------------------------------------------------------------------------
template <int P>
__global__ __launch_bounds__(256) void gemm_bf(
    const unsigned short* __restrict__ Ah, const unsigned short* __restrict__ Al,
    const unsigned short* __restrict__ Bh, const unsigned short* __restrict__ Bl,
    const float* __restrict__ bias,
    float* __restrict__ outF, unsigned short* __restrict__ outT)
{
    const unsigned short* Ap[2] = {Ah, Al};
    const unsigned short* Bp[2] = {Bh, Bl};

    const int bid = (int)blockIdx.x;             // 0..255
    const int xcd = bid & 7, idx = bid >> 3;     // blocks round-robin XCDs
    const int m0  = (((xcd >> 1) << 2) + (idx & 3)) * 128;   // 4 m-tiles/XCD
    const int h   = ((xcd & 1) << 3) + (idx >> 2);           // 8 h-tiles/XCD

    const int tid = (int)threadIdx.x;
    const int l   = tid & 63, w = tid >> 6;
    const int wr  = w >> 1,  wc = w & 1;
    const int cc  = l & 15,  g  = l >> 4;

    __shared__ short As[P][128][40];
    __shared__ short Bs[P][128][40];

    f32x4 acc[4][4] = {};
    bf16x8 ra[P][2], rb[P][2];

    auto LOADSTEP = [&](int k0){
        #pragma unroll
        for (int p = 0; p < P; ++p)
            #pragma unroll
            for (int it = 0; it < 2; ++it){
                int c = tid + it * 256;                  // 0..511
                int row = c >> 2, col8 = (c & 3) * 8;
                ra[p][it] = *(const bf16x8*)&Ap[p][(size_t)(m0 + row) * 2048 + k0 + col8];
                rb[p][it] = *(const bf16x8*)&Bp[p][(size_t)(h * 128 + row) * 2048 + k0 + col8];
            }
    };
    auto STORESTEP = [&](){
        #pragma unroll
        for (int p = 0; p < P; ++p)
            #pragma unroll
            for (int it = 0; it < 2; ++it){
                int c = tid + it * 256;
                int row = c >> 2, col8 = (c & 3) * 8;
                *(bf16x8*)&As[p][row][col8] = ra[p][it];
                *(bf16x8*)&Bs[p][row][col8] = rb[p][it];
            }
    };

    LOADSTEP(0); STORESTEP(); __syncthreads();
    for (int k0 = 0; k0 < 2048; k0 += 32){
        bool more = (k0 + 32) < 2048;
        if (more) LOADSTEP(k0 + 32);

        bf16x8 ah[4], bh[4];
        #pragma unroll
        for (int mt = 0; mt < 4; ++mt)
            ah[mt] = *(const bf16x8*)&As[0][wr * 64 + mt * 16 + cc][g * 8];
        #pragma unroll
        for (int nt = 0; nt < 4; ++nt)
            bh[nt] = *(const bf16x8*)&Bs[0][wc * 64 + nt * 16 + cc][g * 8];
        if (P == 2){
            bf16x8 al[4], bl[4];
            #pragma unroll
            for (int mt = 0; mt < 4; ++mt)
                al[mt] = *(const bf16x8*)&As[P - 1][wr * 64 + mt * 16 + cc][g * 8];
            #pragma unroll
            for (int nt = 0; nt < 4; ++nt)
                bl[nt] = *(const bf16x8*)&Bs[P - 1][wc * 64 + nt * 16 + cc][g * 8];
            #pragma unroll
            for (int mt = 0; mt < 4; ++mt)
                #pragma unroll
                for (int nt = 0; nt < 4; ++nt){
                    acc[mt][nt] = mfma16(ah[mt], bh[nt], acc[mt][nt]);
                    acc[mt][nt] = mfma16(ah[mt], bl[nt], acc[mt][nt]);
                    acc[mt][nt] = mfma16(al[mt], bh[nt], acc[mt][nt]);
                }
        } else {
            #pragma unroll
            for (int mt = 0; mt < 4; ++mt)
                #pragma unroll
                for (int nt = 0; nt < 4; ++nt)
                    acc[mt][nt] = mfma16(ah[mt], bh[nt], acc[mt][nt]);
        }
        __syncthreads();
        if (more){ STORESTEP(); __syncthreads(); }
    }

    #pragma unroll
    for (int mt = 0; mt < 4; ++mt)
        #pragma unroll
        for (int nt = 0; nt < 4; ++nt)
            #pragma unroll
            for (int j = 0; j < 4; ++j){
                int srow = m0 + wr * 64 + mt * 16 + g * 4 + j;
                int col  = wc * 64 + nt * 16 + cc;
                float v = acc[mt][nt][j] + bias[h * 128 + col];
                if (outF) outF[((size_t)h * 2048 + srow) * 128 + col] = v;
                else      outT[((size_t)h * 128 + col) * 2048 + srow] = f2bfu(v);
            }
}

// ---------------------------------------------------------------------------
// In-place RoPE on qf/kf (f32) + emit bf16 copies qbb/kbb.
// ---------------------------------------------------------------------------
__global__ __launch_bounds__(256) void rope_apply(
    float* __restrict__ qf, float* __restrict__ kf,
    unsigned short* __restrict__ qbb, unsigned short* __restrict__ kbb,
    const float* __restrict__ ct, const float* __restrict__ st)
{
    int idx = blockIdx.x * 256 + (int)threadIdx.x;
    int j = idx & 63;
    int s = (idx >> 6) & 2047;
    int h = (idx >> 17) & 15;
    int a = idx >> 21;
    size_t off = ((size_t)h * 2048 + s) * 128;
    float* p = (a ? kf : qf) + off;
    unsigned short* pb = (a ? kbb : qbb) + off;
    float c = ct[s * 64 + j], sn = st[s * 64 + j];
    float x1 = p[j], x2 = p[j + 64];
    float y1 = x1 * c - x2 * sn;
    float y2 = x2 * c + x1 * sn;
    p[j]      = y1;  p[j + 64]  = y2;
    pb[j] = f2bfu(y1); pb[j + 64] = f2bfu(y2);
}

// ---------------------------------------------------------------------------
// Block means: k_cmp from roped f32 K; v_cmp from transposed bf16 V.
// ---------------------------------------------------------------------------
__global__ __launch_bounds__(256) void cmp_mean(
    const float* __restrict__ kf, const unsigned short* __restrict__ vtbf,
    float* __restrict__ kcmp, float* __restrict__ vcmp)
{
    int idx = blockIdx.x * 256 + (int)threadIdx.x;   // 16*64*128
    int d  = idx & 127;
    int nb = (idx >> 7) & 63;
    int h  = idx >> 13;
    const float* kp = &kf[((size_t)h * 2048 + nb * 32) * 128 + d];
    float sk = 0.f;
    #pragma unroll
    for (int t = 0; t < 32; ++t) sk += kp[t * 128];
    const unsigned short* vp = &vtbf[((size_t)h * 128 + d) * 2048 + nb * 32];
    float sv = 0.f;
    #pragma unroll
    for (int t = 0; t < 32; ++t) sv += bf2f(vp[t]);
    kcmp[((size_t)h * 64 + nb) * 128 + d] = sk * 0.03125f;
    vcmp[((size_t)h * 64 + nb) * 128 + d] = sv * 0.03125f;
}

// ---------------------------------------------------------------------------
// Compressed attention + top-8 selection + gates, tiled per (qtile, head).
// ---------------------------------------------------------------------------
__global__ __launch_bounds__(256) void cmp_attn(
    const float* __restrict__ qf, const float* __restrict__ kcmp,
    const float* __restrict__ vcmp,
    const float* __restrict__ Wg, const float* __restrict__ bg,
    float* __restrict__ out, float* __restrict__ gout,
    unsigned long long* __restrict__ bmask)
{
    const int h = blockIdx.y, qt = blockIdx.x, i0 = qt * 64;
    const int tid = (int)threadIdx.x;
    const int l = tid & 63, w = tid >> 6;
    const int ty = tid >> 4, tx = tid & 15;
    const int cc = l & 15, g = l >> 4;

    __shared__ __align__(16) char smem[65536];
    __shared__ float sgl[4][16][3];
    float4* qs4 = (float4*)smem;                                  // [64][32]
    float4* kc4 = (float4*)(smem + 32768);                        // [64][32]
    unsigned short* vcT = (unsigned short*)smem;                  // [128][72]
    float* sc = (float*)(smem + 32768);                           // [64][68]
    unsigned short* ps = (unsigned short*)(smem + 32768 + 17408); // [64][72]

    // ---- stage Q tile and k_cmp (f32, XOR-swizzled float4 chunks) ----
    #pragma unroll
    for (int it = 0; it < 8; ++it){
        int idx = tid + it * 256;            // 0..2047
        int row = idx >> 5, c = idx & 31;
        int cs = c ^ ((row >> 2) & 7);
        qs4[row * 32 + cs] = *(const float4*)&qf[((size_t)h * 2048 + i0 + row) * 128 + c * 4];
        kc4[row * 32 + cs] = *(const float4*)&kcmp[((size_t)h * 64 + row) * 128 + c * 4];
    }
    __syncthreads();

    // ---- gates for this wave's 16 queries (Q already in LDS) ----
    {
        int gi = l & 3, qq = l >> 2;
        if (gi < 3){
            int q = w * 16 + qq;
            float acc = 0.f;
            #pragma unroll
            for (int c = 0; c < 32; ++c){
                float4 qv = qs4[q * 32 + (c ^ ((q >> 2) & 7))];
                const float* wgp = &Wg[(size_t)h * 384 + (c * 4) * 3 + gi];
                acc += qv.x * wgp[0] + qv.y * wgp[3] + qv.z * wgp[6] + qv.w * wgp[9];
            }
            float gv = 1.f / (1.f + expf(-(acc + bg[gi])));
            sgl[w][qq][gi] = gv;
            gout[((size_t)h * 2048 + i0 + q) * 3 + gi] = gv;
        }
    }

    // ---- scores: 64x64x128 f32, 4 rows x 4 cols per thread ----
    float acc[4][4] = {};
    #pragma unroll 2
    for (int k0 = 0; k0 < 32; ++k0){
        float4 qv[4], kv[4];
        #pragma unroll
        for (int j = 0; j < 4; ++j) qv[j] = qs4[(4 * ty + j) * 32 + (k0 ^ (ty & 7))];
        #pragma unroll
        for (int c = 0; c < 4; ++c) kv[c] = kc4[(4 * tx + c) * 32 + (k0 ^ (tx & 7))];
        #pragma unroll
        for (int j = 0; j < 4; ++j)
            #pragma unroll
            for (int c = 0; c < 4; ++c)
                acc[j][c] += qv[j].x * kv[c].x + qv[j].y * kv[c].y
                           + qv[j].z * kv[c].z + qv[j].w * kv[c].w;
    }
    __syncthreads();

    // ---- masked scores -> sc; stage v_cmp^T bf16 -> vcT ----
    #pragma unroll
    for (int j = 0; j < 4; ++j){
        int r = 4 * ty + j, i = i0 + r;
        float4 sv;
        float* svp = (float*)&sv;
        #pragma unroll
        for (int c = 0; c < 4; ++c){
            int b = 4 * tx + c;
            svp[c] = (b * 32 + 31 <= i) ? acc[j][c] * SCALE_F : -1e9f;
        }
        *(float4*)&sc[r * 68 + 4 * tx] = sv;
    }
    #pragma unroll
    for (int it = 0; it < 8; ++it){
        int idx = tid + it * 256;            // 0..2047
        int jb = idx >> 5, d4 = (idx & 31) * 4;
        float4 vx = *(const float4*)&vcmp[((size_t)h * 64 + jb) * 128 + d4];
        const float* vp = (const float*)&vx;
        #pragma unroll
        for (int jj = 0; jj < 4; ++jj)
            vcT[(d4 + jj) * 72 + jb] = f2bfu(vp[jj]);
    }
    __syncthreads();

    // ---- per-wave softmax + top-8 (16 queries per wave) ----
    for (int qq = 0; qq < 16; ++qq){
        const int q = w * 16 + qq;
        float s = sc[q * 68 + l];
        float mx = s;
        #pragma unroll
        for (int off = 1; off < 64; off <<= 1) mx = fmaxf(mx, __shfl_xor(mx, off));
        float p = expf(s - mx);
        float sum = p;
        #pragma unroll
        for (int off = 1; off < 64; off <<= 1) sum += __shfl_xor(sum, off);
        p /= sum;
        ps[q * 72 + l] = f2bfu(p);

        unsigned long long sel = 1ULL << ((i0 + q) >> 5);
        unsigned long long key = (1ULL << 45) |
            ((unsigned long long)__builtin_bit_cast(unsigned, p) << 7) |
            (unsigned long long)(63 - l);
        #pragma unroll
        for (int it = 0; it < 8; ++it){
            unsigned long long k2 = key;
            #pragma unroll
            for (int off = 1; off < 64; off <<= 1){
                unsigned long long o = __shfl_xor(k2, off);
                k2 = (o > k2) ? o : k2;
            }
            int wb = 63 - (int)(k2 & 63ULL);
            sel |= 1ULL << wb;
            if (l == wb) key = 0ULL;
        }
        if (l == 0) bmask[(size_t)h * 2048 + i0 + q] = sel;
    }
    __syncthreads();

    // ---- PV via bf16 MFMA; write base layer g0*out_cmp ----
    f32x4 oacc[8] = {};
    #pragma unroll
    for (int kk = 0; kk < 2; ++kk){
        bf16x8 pa = *(const bf16x8*)&ps[(w * 16 + cc) * 72 + kk * 32 + g * 8];
        #pragma unroll
        for (int nt2 = 0; nt2 < 8; ++nt2){
            bf16x8 vfr = *(const bf16x8*)&vcT[(nt2 * 16 + cc) * 72 + kk * 32 + g * 8];
            oacc[nt2] = mfma16(pa, vfr, oacc[nt2]);
        }
    }
    #pragma unroll
    for (int j = 0; j < 4; ++j){
        int q = w * 16 + g * 4 + j, iq = i0 + q;
        float g0 = sgl[w][g * 4 + j][0];
        float f = (iq >= 31) ? g0 : 0.f;
        #pragma unroll
        for (int nt2 = 0; nt2 < 8; ++nt2)
            out[(size_t)iq * 2048 + h * 128 + nt2 * 16 + cc] = f * oacc[nt2][j];
    }
}

// ---------------------------------------------------------------------------
// Split-K sparse attention with fixed-max (max=0) softmax in exp2 domain.
// Grid: 1280 blocks = 16 heads x 80 (qt,seg) units; qt in group g in [0,4)
// has g+1 segments.  Shared QK^T feeds sel-mask and win-mask P/PV passes.
// Partials (O', l') accumulated to global via atomicAdd (associative).
// Window spans chunks qt-8 .. qt (9 chunks).
// ---------------------------------------------------------------------------
__global__ __launch_bounds__(256) void attn_fd(
    const unsigned short* __restrict__ qbf,   // [h][s][128] bf16
    const unsigned short* __restrict__ kbf,   // [h][s][128] bf16
    const unsigned short* __restrict__ vtbf,  // [h][128][2048] bf16 (V^T)
    const unsigned long long* __restrict__ bmask,
    float* __restrict__ Osel, float* __restrict__ lsel,   // [h][s][128],[h][s]
    float* __restrict__ Owin, float* __restrict__ lwin)
{
    // ---- decode block -> (h, qt, seg), heavy groups first ----
    const int bx = (int)blockIdx.x;
    const int h  = bx & 15;
    const int rr = 79 - (bx >> 4);
    const int g4 = (rr >= 48) ? 3 : (rr >= 24) ? 2 : (rr >= 8) ? 1 : 0;
    const int r  = rr - 4 * g4 * (g4 + 1);
    const int qt = 8 * g4 + r / (g4 + 1);
    const int seg = r % (g4 + 1);
    const int nch = qt + 1, nseg = g4 + 1;
    const int chlo = seg * nch / nseg;
    const int chhi = (seg + 1) * nch / nseg;      // exclusive

    const int i0 = qt * 64;
    const int tid = (int)threadIdx.x;
    const int l = tid & 63, w = tid >> 6;
    const int cc = l & 15,  g = l >> 4;

    __shared__ short Ks[64][136];     // K chunk [tok][d], +8 pad
    __shared__ short Vt[128][72];     // V^T chunk [d][tok], +8 pad
    __shared__ short Ps[4][16][72];   // P [wave][row][tok], +8 pad

    // union of selected-block masks over this tile's 64 queries
    unsigned long long um = bmask[(size_t)h * 2048 + i0 + l];
    #pragma unroll
    for (int off = 1; off < 64; off <<= 1) um |= __shfl_xor(um, off);

    unsigned long long bm[4];
    int mrow[4];
    #pragma unroll
    for (int j = 0; j < 4; ++j){
        mrow[j] = i0 + w * 16 + g * 4 + j;
        bm[j] = bmask[(size_t)h * 2048 + mrow[j]];
    }

    bf16x8 qfrag[4];
    {
        const unsigned short* qrow = &qbf[((size_t)h * 2048 + i0 + w * 16 + cc) * 128];
        #pragma unroll
        for (int kk = 0; kk < 4; ++kk)
            qfrag[kk] = *(const bf16x8*)&qrow[kk * 32 + g * 8];
    }

    f32x4 oaccS[8] = {}, oaccW[8] = {};
    float lsumS[4] = {}, lsumW[4] = {};

    auto needed = [&](int ch)->bool {
        return (ch >= qt - 8) || (((um >> (2 * ch)) & 3ULL) != 0ULL);
    };

    bf16x8 rk[4], rv[4];
    auto LOADC = [&](int ch){
        #pragma unroll
        for (int it = 0; it < 4; ++it){
            int c = tid + it * 256;
            rk[it] = *(const bf16x8*)&kbf[((size_t)h * 2048 + ch * 64 + (c >> 4)) * 128 + (c & 15) * 8];
            rv[it] = *(const bf16x8*)&vtbf[((size_t)h * 128 + (c >> 3)) * 2048 + ch * 64 + (c & 7) * 8];
        }
    };
    auto STOREC = [&](){
        #pragma unroll
        for (int it = 0; it < 4; ++it){
            int c = tid + it * 256;
            *(bf16x8*)&Ks[c >> 4][(c & 15) * 8] = rk[it];
            *(bf16x8*)&Vt[c >> 3][(c & 7) * 8] = rv[it];
        }
    };

    int cur = chlo;
    while (cur < chhi && !needed(cur)) ++cur;
    if (cur < chhi){
        LOADC(cur); STOREC(); __syncthreads();

        while (cur < chhi){
            int nxt = cur + 1;
            while (nxt < chhi && !needed(nxt)) ++nxt;
            const bool more = (nxt < chhi);
            if (more) LOADC(nxt);

            // ---- shared QK^T ----
            f32x4 sacc[4] = {};
            #pragma unroll
            for (int kk = 0; kk < 4; ++kk)
                #pragma unroll
                for (int nt = 0; nt < 4; ++nt){
                    bf16x8 kfr = *(const bf16x8*)&Ks[nt * 16 + cc][kk * 32 + g * 8];
                    sacc[nt] = mfma16(qfrag[kk], kfr, sacc[nt]);
                }

            // ---- fixed-max exp (exp2 domain), shared by both branches ----
            float pe[4][4];
            #pragma unroll
            for (int j = 0; j < 4; ++j)
                #pragma unroll
                for (int nt = 0; nt < 4; ++nt)
                    pe[j][nt] = exp2f(sacc[nt][j] * SCL2E);

            const int tbase = cur * 64;

            // ---- SEL branch: mask, P->LDS, PV ----
            #pragma unroll
            for (int j = 0; j < 4; ++j){
                const int iq = mrow[j];
                const int row = g * 4 + j;
                float pacc = 0.f;
                #pragma unroll
                for (int nt = 0; nt < 4; ++nt){
                    int t = tbase + nt * 16 + cc;
                    bool o = (t <= iq) && (((bm[j] >> (t >> 5)) & 1ULL) != 0ULL);
                    float p = o ? pe[j][nt] : 0.f;
                    pacc += p;
                    Ps[w][row][nt * 16 + cc] = (short)f2bfu(p);
                }
                lsumS[j] += pacc;
            }
            #pragma unroll
            for (int kk = 0; kk < 2; ++kk){
                bf16x8 pa = *(const bf16x8*)&Ps[w][cc][kk * 32 + g * 8];
                #pragma unroll
                for (int nt2 = 0; nt2 < 8; ++nt2){
                    bf16x8 vfr = *(const bf16x8*)&Vt[nt2 * 16 + cc][kk * 32 + g * 8];
                    oaccS[nt2] = mfma16(pa, vfr, oaccS[nt2]);
                }
            }

            // ---- WIN branch (chunks qt-8 .. qt can contribute) ----
            if (cur >= qt - 8){
                #pragma unroll
                for (int j = 0; j < 4; ++j){
                    const int iq = mrow[j];
                    const int row = g * 4 + j;
                    float pacc = 0.f;
                    #pragma unroll
                    for (int nt = 0; nt < 4; ++nt){
                        int t = tbase + nt * 16 + cc;
                        bool o = (t <= iq) && ((iq - t) < 512);
                        float p = o ? pe[j][nt] : 0.f;
                        pacc += p;
                        Ps[w][row][nt * 16 + cc] = (short)f2bfu(p);
                    }
                    lsumW[j] += pacc;
                }
                #pragma unroll
                for (int kk = 0; kk < 2; ++kk){
                    bf16x8 pa = *(const bf16x8*)&Ps[w][cc][kk * 32 + g * 8];
                    #pragma unroll
                    for (int nt2 = 0; nt2 < 8; ++nt2){
                        bf16x8 vfr = *(const bf16x8*)&Vt[nt2 * 16 + cc][kk * 32 + g * 8];
                        oaccW[nt2] = mfma16(pa, vfr, oaccW[nt2]);
                    }
                }
            }

            __syncthreads();                // all waves done reading Ks/Vt
            if (more){ STOREC(); __syncthreads(); }
            cur = more ? nxt : chhi;
        }
    }

    // ---- epilogue: atomicAdd partials ----
    #pragma unroll
    for (int j = 0; j < 4; ++j){
        const int iq = mrow[j];
        float ls = lsumS[j], lw = lsumW[j];
        #pragma unroll
        for (int off = 1; off < 16; off <<= 1){
            ls += __shfl_xor(ls, off);
            lw += __shfl_xor(lw, off);
        }
        if (cc == 0){
            atomicAdd(&lsel[(size_t)h * 2048 + iq], ls);
            atomicAdd(&lwin[(size_t)h * 2048 + iq], lw);
        }
        #pragma unroll
        for (int nt2 = 0; nt2 < 8; ++nt2){
            size_t po = ((size_t)h * 2048 + iq) * 128 + nt2 * 16 + cc;
            atomicAdd(&Osel[po], oaccS[nt2][j]);
            atomicAdd(&Owin[po], oaccW[nt2][j]);
        }
    }
}

// ---------------------------------------------------------------------------
// Finalize: out += g1 * Osel/lsel + g2 * Owin/lwin.
// ---------------------------------------------------------------------------
__global__ __launch_bounds__(256) void finalize(
    const float* __restrict__ Osel, const float* __restrict__ lsel,
    const float* __restrict__ Owin, const float* __restrict__ lwin,
    const float* __restrict__ gates, float* __restrict__ out)
{
    int idx = blockIdx.x * 256 + (int)threadIdx.x;   // 0..1048575
    int d4 = (idx & 31) * 4;
    int s  = (idx >> 5) & 2047;
    int h  = idx >> 16;
    size_t hs = (size_t)h * 2048 + s;
    float g1 = gates[hs * 3 + 1], g2 = gates[hs * 3 + 2];
    float il = g1 / lsel[hs];
    float iw = g2 / lwin[hs];
    size_t po = hs * 128 + d4;
    float4 a = *(const float4*)&Osel[po];
    float4 b = *(const float4*)&Owin[po];
    float* op = &out[(size_t)s * 2048 + h * 128 + d4];
    float4 o = *(const float4*)op;
    o.x += a.x * il + b.x * iw;
    o.y += a.y * il + b.y * iw;
    o.z += a.z * il + b.z * iw;
    o.w += a.w * il + b.w * iw;
    *(float4*)op = o;
}

// ---------------------------------------------------------------------------
extern "C" void kernel_launch(void* const* d_in, const int* in_sizes, int n_in,
                              void* d_out, int out_size, void* d_ws, size_t ws_size,
                              hipStream_t stream)
{
    const float* X  = (const float*)d_in[0];
    const float* Wq = (const float*)d_in[1];
    const float* bq = (const float*)d_in[2];
    const float* Wk = (const float*)d_in[3];
    const float* bk = (const float*)d_in[4];
    const float* Wv = (const float*)d_in[5];
    const float* bv = (const float*)d_in[6];
    const float* Wg = (const float*)d_in[7];
    const float* bg = (const float*)d_in[8];
    float* out = (float*)d_out;

    const size_t MBs = (size_t)1 << 20;
    char* ws = (char*)d_ws;

    unsigned short* Xh  = (unsigned short*)(ws + 0 * MBs);
    unsigned short* Xl  = (unsigned short*)(ws + 8 * MBs);
    unsigned short* WTh = (unsigned short*)(ws + 16 * MBs);
    unsigned short* WTl = (unsigned short*)(ws + 24 * MBs);
    float* qf  = (float*)(ws + 32 * MBs);
    float* kf  = (float*)(ws + 48 * MBs);
    unsigned short* vtbf = (unsigned short*)(ws + 64 * MBs);
    unsigned short* qbf  = (unsigned short*)(ws + 16 * MBs);  // alias (W dead)
    unsigned short* kbf  = (unsigned short*)(ws + 24 * MBs);  // alias
    float* Osel = (float*)(ws + 0 * MBs);    // alias Xh/Xl (dead after gemms)
    float* Owin = (float*)(ws + 32 * MBs);   // alias qf (dead after cmp_attn)
    const size_t SM = 72 * MBs;
    float* cost  = (float*)(ws + SM);
    float* sint  = (float*)(ws + SM + 524288);
    float* kcmp  = (float*)(ws + SM + 1048576);
    float* vcmp  = (float*)(ws + SM + 1572864);
    float* gatesb = (float*)(ws + SM + 2097152);
    unsigned long long* bmaskb = (unsigned long long*)(ws + SM + 2490368);
    float* lsel = (float*)(ws + SM + 2752512);
    float* lwin = (float*)(ws + SM + 2883584);   // ends ~72MB+2.9MB

    rope_table_k<<<2048, 64, 0, stream>>>(cost, sint);
    prep_split<<<4096, 256, 0, stream>>>(X, Xh, Xl);

    prep_wT<<<dim3(32, 32), 256, 0, stream>>>(Wq, WTh, WTl);
    gemm_bf<2><<<256, 256, 0, stream>>>(Xh, Xl, WTh, WTl, bq, qf, nullptr);
    prep_wT<<<dim3(32, 32), 256, 0, stream>>>(Wk, WTh, WTl);
    gemm_bf<2><<<256, 256, 0, stream>>>(Xh, Xl, WTh, WTl, bk, kf, nullptr);
    prep_wT<<<dim3(32, 32), 256, 0, stream>>>(Wv, WTh, nullptr);
    gemm_bf<1><<<256, 256, 0, stream>>>(Xh, nullptr, WTh, nullptr, bv, nullptr, vtbf);

    rope_apply<<<16384, 256, 0, stream>>>(qf, kf, qbf, kbf, cost, sint);
    cmp_mean<<<512, 256, 0, stream>>>(kf, vtbf, kcmp, vcmp);
    cmp_attn<<<dim3(32, 16), 256, 0, stream>>>(qf, kcmp, vcmp, Wg, bg,
                                               out, gatesb, bmaskb);

    // zero split-K partials (Xh/Xl and qf regions are dead by now in-stream)
    hipMemsetAsync(Osel, 0, 16 * MBs, stream);
    hipMemsetAsync(Owin, 0, 16 * MBs, stream);
    hipMemsetAsync(lsel, 0, 262144, stream);

    attn_fd<<<1280, 256, 0, stream>>>(qbf, kbf, vtbf, bmaskb,
                                      Osel, lsel, Owin, lwin);
    finalize<<<4096, 256, 0, stream>>>(Osel, lsel, Owin, lwin, gatesb, out);
}

// Round 9
// 558.751 us; speedup vs baseline: 2.3104x; 1.0589x over previous
//
#include <hip/hip_runtime.h>

// ---------------------------------------------------------------------------
// NSA attention forward, B=1, S=2048, HID=2048, H=16, D=128, L=32, NB=64,
// NSEL=8, WIN=512.  f32 in/out.  Round 9: split-K attention partials written
// as plain bf16 stores into per-segment slots (no O atomics); finalize
// gathers <=4 sel + <=2 win slots.  Sel pass skipped on window-only chunks.
// ---------------------------------------------------------------------------

#define SCALE_F 0.08838834764831845f                         // 1/sqrt(128)
#define SCL2E   (0.08838834764831845f * 1.4426950408889634f) // SCALE*log2(e)

typedef short  bf16x8 __attribute__((ext_vector_type(8)));
typedef short  s16x4  __attribute__((ext_vector_type(4)));
typedef float  f32x4  __attribute__((ext_vector_type(4)));

__device__ __forceinline__ unsigned short f2bfu(float x){
    unsigned u = __builtin_bit_cast(unsigned, x);
    u = (u + 0x7FFFu + ((u >> 16) & 1u)) >> 16;   // RNE
    return (unsigned short)u;
}
__device__ __forceinline__ float bf2f(unsigned short b){
    unsigned u = ((unsigned)b) << 16;
    return __builtin_bit_cast(float, u);
}
__device__ __forceinline__ f32x4 mfma16(bf16x8 a, bf16x8 b, f32x4 c){
    return __builtin_amdgcn_mfma_f32_16x16x32_bf16(a, b, c, 0, 0, 0);
}

// ---------------------------------------------------------------------------
// RoPE tables (f32 math mirroring reference)
// ---------------------------------------------------------------------------
__global__ __launch_bounds__(64) void rope_table_k(float* __restrict__ ct,
                                                   float* __restrict__ st){
    int s = blockIdx.x, j = threadIdx.x;
    float fr  = 1.0f / powf(10000.0f, (float)j * (1.0f / 64.0f));
    float ang = (float)s * fr;
    ct[s * 64 + j] = cosf(ang);
    st[s * 64 + j] = sinf(ang);
}

// ---------------------------------------------------------------------------
// X f32 -> bf16 hi + lo planes.  4 floats/thread.
// ---------------------------------------------------------------------------
__global__ __launch_bounds__(256) void prep_split(const float* __restrict__ src,
                                                  unsigned short* __restrict__ hi,
                                                  unsigned short* __restrict__ lo){
    size_t i = ((size_t)blockIdx.x * 256 + threadIdx.x) * 4;
    float4 x = *(const float4*)&src[i];
    unsigned short h0 = f2bfu(x.x), h1 = f2bfu(x.y), h2 = f2bfu(x.z), h3 = f2bfu(x.w);
    s16x4 hv; hv[0] = (short)h0; hv[1] = (short)h1; hv[2] = (short)h2; hv[3] = (short)h3;
    *(s16x4*)&hi[i] = hv;
    s16x4 lv;
    lv[0] = (short)f2bfu(x.x - bf2f(h0)); lv[1] = (short)f2bfu(x.y - bf2f(h1));
    lv[2] = (short)f2bfu(x.z - bf2f(h2)); lv[3] = (short)f2bfu(x.w - bf2f(h3));
    *(s16x4*)&lo[i] = lv;
}

// ---------------------------------------------------------------------------
// W (2048x2048, [k][n]) -> W^T bf16 planes ([n][k]), hi + optional lo.
// ---------------------------------------------------------------------------
__global__ __launch_bounds__(256) void prep_wT(const float* __restrict__ W,
                                               unsigned short* __restrict__ Th,
                                               unsigned short* __restrict__ Tl){
    __shared__ float T[64][65];
    const int k0 = blockIdx.x * 64, n0 = blockIdx.y * 64;
    const int tid = (int)threadIdx.x;
    #pragma unroll
    for (int it = 0; it < 16; ++it){
        int idx = tid + it * 256;
        int r = idx >> 6, c = idx & 63;
        T[c][r] = W[(size_t)(k0 + r) * 2048 + n0 + c];
    }
    __syncthreads();
    #pragma unroll
    for (int it = 0; it < 16; ++it){
        int idx = tid + it * 256;
        int n = idx >> 6, k = idx & 63;
        float v = T[n][k];
        unsigned short h = f2bfu(v);
        Th[(size_t)(n0 + n) * 2048 + k0 + k] = h;
        if (Tl) Tl[(size_t)(n0 + n) * 2048 + k0 + k] = f2bfu(v - bf2f(h));
    }
}

// ---------------------------------------------------------------------------
// GEMM from pre-converted bf16 planes.  C = A @ B^T_planes + bias.
// 128x128 tile, BK=32, 4 waves, reg-prefetch double-buffering, XCD-rect
// swizzle (each XCD owns a 4m x 8h rectangle).
// ---------------------------------------------------------------------------
template <int P>
__global__ __launch_bounds__(256) void gemm_bf(
    const unsigned short* __restrict__ Ah, const unsigned short* __restrict__ Al,
    const unsigned short* __restrict__ Bh, const unsigned short* __restrict__ Bl,
    const float* __restrict__ bias,
    float* __restrict__ outF, unsigned short* __restrict__ outT)
{
    const unsigned short* Ap[2] = {Ah, Al};
    const unsigned short* Bp[2] = {Bh, Bl};

    const int bid = (int)blockIdx.x;             // 0..255
    const int xcd = bid & 7, idx = bid >> 3;     // blocks round-robin XCDs
    const int m0  = (((xcd >> 1) << 2) + (idx & 3)) * 128;   // 4 m-tiles/XCD
    const int h   = ((xcd & 1) << 3) + (idx >> 2);           // 8 h-tiles/XCD

    const int tid = (int)threadIdx.x;
    const int l   = tid & 63, w = tid >> 6;
    const int wr  = w >> 1,  wc = w & 1;
    const int cc  = l & 15,  g  = l >> 4;

    __shared__ short As[P][128][40];
    __shared__ short Bs[P][128][40];

    f32x4 acc[4][4] = {};
    bf16x8 ra[P][2], rb[P][2];

    auto LOADSTEP = [&](int k0){
        #pragma unroll
        for (int p = 0; p < P; ++p)
            #pragma unroll
            for (int it = 0; it < 2; ++it){
                int c = tid + it * 256;                  // 0..511
                int row = c >> 2, col8 = (c & 3) * 8;
                ra[p][it] = *(const bf16x8*)&Ap[p][(size_t)(m0 + row) * 2048 + k0 + col8];
                rb[p][it] = *(const bf16x8*)&Bp[p][(size_t)(h * 128 + row) * 2048 + k0 + col8];
            }
    };
    auto STORESTEP = [&](){
        #pragma unroll
        for (int p = 0; p < P; ++p)
            #pragma unroll
            for (int it = 0; it < 2; ++it){
                int c = tid + it * 256;
                int row = c >> 2, col8 = (c & 3) * 8;
                *(bf16x8*)&As[p][row][col8] = ra[p][it];
                *(bf16x8*)&Bs[p][row][col8] = rb[p][it];
            }
    };

    LOADSTEP(0); STORESTEP(); __syncthreads();
    for (int k0 = 0; k0 < 2048; k0 += 32){
        bool more = (k0 + 32) < 2048;
        if (more) LOADSTEP(k0 + 32);

        bf16x8 ah[4], bh[4];
        #pragma unroll
        for (int mt = 0; mt < 4; ++mt)
            ah[mt] = *(const bf16x8*)&As[0][wr * 64 + mt * 16 + cc][g * 8];
        #pragma unroll
        for (int nt = 0; nt < 4; ++nt)
            bh[nt] = *(const bf16x8*)&Bs[0][wc * 64 + nt * 16 + cc][g * 8];
        if (P == 2){
            bf16x8 al[4], bl[4];
            #pragma unroll
            for (int mt = 0; mt < 4; ++mt)
                al[mt] = *(const bf16x8*)&As[P - 1][wr * 64 + mt * 16 + cc][g * 8];
            #pragma unroll
            for (int nt = 0; nt < 4; ++nt)
                bl[nt] = *(const bf16x8*)&Bs[P - 1][wc * 64 + nt * 16 + cc][g * 8];
            #pragma unroll
            for (int mt = 0; mt < 4; ++mt)
                #pragma unroll
                for (int nt = 0; nt < 4; ++nt){
                    acc[mt][nt] = mfma16(ah[mt], bh[nt], acc[mt][nt]);
                    acc[mt][nt] = mfma16(ah[mt], bl[nt], acc[mt][nt]);
                    acc[mt][nt] = mfma16(al[mt], bh[nt], acc[mt][nt]);
                }
        } else {
            #pragma unroll
            for (int mt = 0; mt < 4; ++mt)
                #pragma unroll
                for (int nt = 0; nt < 4; ++nt)
                    acc[mt][nt] = mfma16(ah[mt], bh[nt], acc[mt][nt]);
        }
        __syncthreads();
        if (more){ STORESTEP(); __syncthreads(); }
    }

    #pragma unroll
    for (int mt = 0; mt < 4; ++mt)
        #pragma unroll
        for (int nt = 0; nt < 4; ++nt)
            #pragma unroll
            for (int j = 0; j < 4; ++j){
                int srow = m0 + wr * 64 + mt * 16 + g * 4 + j;
                int col  = wc * 64 + nt * 16 + cc;
                float v = acc[mt][nt][j] + bias[h * 128 + col];
                if (outF) outF[((size_t)h * 2048 + srow) * 128 + col] = v;
                else      outT[((size_t)h * 128 + col) * 2048 + srow] = f2bfu(v);
            }
}

// ---------------------------------------------------------------------------
// In-place RoPE on qf/kf (f32) + emit bf16 copies qbb/kbb.
// ---------------------------------------------------------------------------
__global__ __launch_bounds__(256) void rope_apply(
    float* __restrict__ qf, float* __restrict__ kf,
    unsigned short* __restrict__ qbb, unsigned short* __restrict__ kbb,
    const float* __restrict__ ct, const float* __restrict__ st)
{
    int idx = blockIdx.x * 256 + (int)threadIdx.x;
    int j = idx & 63;
    int s = (idx >> 6) & 2047;
    int h = (idx >> 17) & 15;
    int a = idx >> 21;
    size_t off = ((size_t)h * 2048 + s) * 128;
    float* p = (a ? kf : qf) + off;
    unsigned short* pb = (a ? kbb : qbb) + off;
    float c = ct[s * 64 + j], sn = st[s * 64 + j];
    float x1 = p[j], x2 = p[j + 64];
    float y1 = x1 * c - x2 * sn;
    float y2 = x2 * c + x1 * sn;
    p[j]      = y1;  p[j + 64]  = y2;
    pb[j] = f2bfu(y1); pb[j + 64] = f2bfu(y2);
}

// ---------------------------------------------------------------------------
// Block means: k_cmp from roped f32 K; v_cmp from transposed bf16 V.
// ---------------------------------------------------------------------------
__global__ __launch_bounds__(256) void cmp_mean(
    const float* __restrict__ kf, const unsigned short* __restrict__ vtbf,
    float* __restrict__ kcmp, float* __restrict__ vcmp)
{
    int idx = blockIdx.x * 256 + (int)threadIdx.x;   // 16*64*128
    int d  = idx & 127;
    int nb = (idx >> 7) & 63;
    int h  = idx >> 13;
    const float* kp = &kf[((size_t)h * 2048 + nb * 32) * 128 + d];
    float sk = 0.f;
    #pragma unroll
    for (int t = 0; t < 32; ++t) sk += kp[t * 128];
    const unsigned short* vp = &vtbf[((size_t)h * 128 + d) * 2048 + nb * 32];
    float sv = 0.f;
    #pragma unroll
    for (int t = 0; t < 32; ++t) sv += bf2f(vp[t]);
    kcmp[((size_t)h * 64 + nb) * 128 + d] = sk * 0.03125f;
    vcmp[((size_t)h * 64 + nb) * 128 + d] = sv * 0.03125f;
}

// ---------------------------------------------------------------------------
// Compressed attention + top-8 selection + gates, tiled per (qtile, head).
// ---------------------------------------------------------------------------
__global__ __launch_bounds__(256) void cmp_attn(
    const float* __restrict__ qf, const float* __restrict__ kcmp,
    const float* __restrict__ vcmp,
    const float* __restrict__ Wg, const float* __restrict__ bg,
    float* __restrict__ out, float* __restrict__ gout,
    unsigned long long* __restrict__ bmask)
{
    const int h = blockIdx.y, qt = blockIdx.x, i0 = qt * 64;
    const int tid = (int)threadIdx.x;
    const int l = tid & 63, w = tid >> 6;
    const int ty = tid >> 4, tx = tid & 15;
    const int cc = l & 15, g = l >> 4;

    __shared__ __align__(16) char smem[65536];
    __shared__ float sgl[4][16][3];
    float4* qs4 = (float4*)smem;                                  // [64][32]
    float4* kc4 = (float4*)(smem + 32768);                        // [64][32]
    unsigned short* vcT = (unsigned short*)smem;                  // [128][72]
    float* sc = (float*)(smem + 32768);                           // [64][68]
    unsigned short* ps = (unsigned short*)(smem + 32768 + 17408); // [64][72]

    // ---- stage Q tile and k_cmp (f32, XOR-swizzled float4 chunks) ----
    #pragma unroll
    for (int it = 0; it < 8; ++it){
        int idx = tid + it * 256;            // 0..2047
        int row = idx >> 5, c = idx & 31;
        int cs = c ^ ((row >> 2) & 7);
        qs4[row * 32 + cs] = *(const float4*)&qf[((size_t)h * 2048 + i0 + row) * 128 + c * 4];
        kc4[row * 32 + cs] = *(const float4*)&kcmp[((size_t)h * 64 + row) * 128 + c * 4];
    }
    __syncthreads();

    // ---- gates for this wave's 16 queries (Q already in LDS) ----
    {
        int gi = l & 3, qq = l >> 2;
        if (gi < 3){
            int q = w * 16 + qq;
            float acc = 0.f;
            #pragma unroll
            for (int c = 0; c < 32; ++c){
                float4 qv = qs4[q * 32 + (c ^ ((q >> 2) & 7))];
                const float* wgp = &Wg[(size_t)h * 384 + (c * 4) * 3 + gi];
                acc += qv.x * wgp[0] + qv.y * wgp[3] + qv.z * wgp[6] + qv.w * wgp[9];
            }
            float gv = 1.f / (1.f + expf(-(acc + bg[gi])));
            sgl[w][qq][gi] = gv;
            gout[((size_t)h * 2048 + i0 + q) * 3 + gi] = gv;
        }
    }

    // ---- scores: 64x64x128 f32, 4 rows x 4 cols per thread ----
    float acc[4][4] = {};
    #pragma unroll 2
    for (int k0 = 0; k0 < 32; ++k0){
        float4 qv[4], kv[4];
        #pragma unroll
        for (int j = 0; j < 4; ++j) qv[j] = qs4[(4 * ty + j) * 32 + (k0 ^ (ty & 7))];
        #pragma unroll
        for (int c = 0; c < 4; ++c) kv[c] = kc4[(4 * tx + c) * 32 + (k0 ^ (tx & 7))];
        #pragma unroll
        for (int j = 0; j < 4; ++j)
            #pragma unroll
            for (int c = 0; c < 4; ++c)
                acc[j][c] += qv[j].x * kv[c].x + qv[j].y * kv[c].y
                           + qv[j].z * kv[c].z + qv[j].w * kv[c].w;
    }
    __syncthreads();

    // ---- masked scores -> sc; stage v_cmp^T bf16 -> vcT ----
    #pragma unroll
    for (int j = 0; j < 4; ++j){
        int r = 4 * ty + j, i = i0 + r;
        float4 sv;
        float* svp = (float*)&sv;
        #pragma unroll
        for (int c = 0; c < 4; ++c){
            int b = 4 * tx + c;
            svp[c] = (b * 32 + 31 <= i) ? acc[j][c] * SCALE_F : -1e9f;
        }
        *(float4*)&sc[r * 68 + 4 * tx] = sv;
    }
    #pragma unroll
    for (int it = 0; it < 8; ++it){
        int idx = tid + it * 256;            // 0..2047
        int jb = idx >> 5, d4 = (idx & 31) * 4;
        float4 vx = *(const float4*)&vcmp[((size_t)h * 64 + jb) * 128 + d4];
        const float* vp = (const float*)&vx;
        #pragma unroll
        for (int jj = 0; jj < 4; ++jj)
            vcT[(d4 + jj) * 72 + jb] = f2bfu(vp[jj]);
    }
    __syncthreads();

    // ---- per-wave softmax + top-8 (16 queries per wave) ----
    for (int qq = 0; qq < 16; ++qq){
        const int q = w * 16 + qq;
        float s = sc[q * 68 + l];
        float mx = s;
        #pragma unroll
        for (int off = 1; off < 64; off <<= 1) mx = fmaxf(mx, __shfl_xor(mx, off));
        float p = expf(s - mx);
        float sum = p;
        #pragma unroll
        for (int off = 1; off < 64; off <<= 1) sum += __shfl_xor(sum, off);
        p /= sum;
        ps[q * 72 + l] = f2bfu(p);

        unsigned long long sel = 1ULL << ((i0 + q) >> 5);
        unsigned long long key = (1ULL << 45) |
            ((unsigned long long)__builtin_bit_cast(unsigned, p) << 7) |
            (unsigned long long)(63 - l);
        #pragma unroll
        for (int it = 0; it < 8; ++it){
            unsigned long long k2 = key;
            #pragma unroll
            for (int off = 1; off < 64; off <<= 1){
                unsigned long long o = __shfl_xor(k2, off);
                k2 = (o > k2) ? o : k2;
            }
            int wb = 63 - (int)(k2 & 63ULL);
            sel |= 1ULL << wb;
            if (l == wb) key = 0ULL;
        }
        if (l == 0) bmask[(size_t)h * 2048 + i0 + q] = sel;
    }
    __syncthreads();

    // ---- PV via bf16 MFMA; write base layer g0*out_cmp ----
    f32x4 oacc[8] = {};
    #pragma unroll
    for (int kk = 0; kk < 2; ++kk){
        bf16x8 pa = *(const bf16x8*)&ps[(w * 16 + cc) * 72 + kk * 32 + g * 8];
        #pragma unroll
        for (int nt2 = 0; nt2 < 8; ++nt2){
            bf16x8 vfr = *(const bf16x8*)&vcT[(nt2 * 16 + cc) * 72 + kk * 32 + g * 8];
            oacc[nt2] = mfma16(pa, vfr, oacc[nt2]);
        }
    }
    #pragma unroll
    for (int j = 0; j < 4; ++j){
        int q = w * 16 + g * 4 + j, iq = i0 + q;
        float g0 = sgl[w][g * 4 + j][0];
        float f = (iq >= 31) ? g0 : 0.f;
        #pragma unroll
        for (int nt2 = 0; nt2 < 8; ++nt2)
            out[(size_t)iq * 2048 + h * 128 + nt2 * 16 + cc] = f * oacc[nt2][j];
    }
}

// ---------------------------------------------------------------------------
// Split-K sparse attention, fixed-max softmax (exp2 domain).  Partial O
// written as plain bf16 stores into per-(h,qt,seg) slots:
//   Psel[h][rr(0..79)][64][128], Pwin[h][wunit(0..55)][64][128]
// (win slots exist only for the <=2 segments that can touch the 9-chunk
// window).  l partials remain tiny f32 atomics.
// ---------------------------------------------------------------------------
__global__ __launch_bounds__(256) void attn_fd(
    const unsigned short* __restrict__ qbf,   // [h][s][128] bf16
    const unsigned short* __restrict__ kbf,   // [h][s][128] bf16
    const unsigned short* __restrict__ vtbf,  // [h][128][2048] bf16 (V^T)
    const unsigned long long* __restrict__ bmask,
    unsigned short* __restrict__ Psel,        // [16][80][64][128] bf16
    unsigned short* __restrict__ Pwin,        // [16][56][64][128] bf16
    float* __restrict__ lsel, float* __restrict__ lwin)   // [h][s] f32 atomics
{
    // ---- decode block -> (h, qt, seg), heavy groups first ----
    const int bx = (int)blockIdx.x;
    const int h  = bx & 15;
    const int rr = 79 - (bx >> 4);
    const int g4 = (rr >= 48) ? 3 : (rr >= 24) ? 2 : (rr >= 8) ? 1 : 0;
    const int r  = rr - 4 * g4 * (g4 + 1);
    const int qt = 8 * g4 + r / (g4 + 1);
    const int seg = r % (g4 + 1);
    const int nch = qt + 1, nseg = g4 + 1;
    const int chlo = seg * nch / nseg;
    const int chhi = (seg + 1) * nch / nseg;      // exclusive

    const int i0 = qt * 64;
    const int tid = (int)threadIdx.x;
    const int l = tid & 63, w = tid >> 6;
    const int cc = l & 15,  g = l >> 4;

    __shared__ short Ks[64][136];     // K chunk [tok][d], +8 pad
    __shared__ short Vt[128][72];     // V^T chunk [d][tok], +8 pad
    __shared__ short Ps[4][16][72];   // P [wave][row][tok], +8 pad

    // union of selected-block masks over this tile's 64 queries
    unsigned long long um = bmask[(size_t)h * 2048 + i0 + l];
    #pragma unroll
    for (int off = 1; off < 64; off <<= 1) um |= __shfl_xor(um, off);

    unsigned long long bm[4];
    int mrow[4];
    #pragma unroll
    for (int j = 0; j < 4; ++j){
        mrow[j] = i0 + w * 16 + g * 4 + j;
        bm[j] = bmask[(size_t)h * 2048 + mrow[j]];
    }

    bf16x8 qfrag[4];
    {
        const unsigned short* qrow = &qbf[((size_t)h * 2048 + i0 + w * 16 + cc) * 128];
        #pragma unroll
        for (int kk = 0; kk < 4; ++kk)
            qfrag[kk] = *(const bf16x8*)&qrow[kk * 32 + g * 8];
    }

    f32x4 oaccS[8] = {}, oaccW[8] = {};
    float lsumS[4] = {}, lsumW[4] = {};

    auto needed = [&](int ch)->bool {
        return (ch >= qt - 8) || (((um >> (2 * ch)) & 3ULL) != 0ULL);
    };

    bf16x8 rk[4], rv[4];
    auto LOADC = [&](int ch){
        #pragma unroll
        for (int it = 0; it < 4; ++it){
            int c = tid + it * 256;
            rk[it] = *(const bf16x8*)&kbf[((size_t)h * 2048 + ch * 64 + (c >> 4)) * 128 + (c & 15) * 8];
            rv[it] = *(const bf16x8*)&vtbf[((size_t)h * 128 + (c >> 3)) * 2048 + ch * 64 + (c & 7) * 8];
        }
    };
    auto STOREC = [&](){
        #pragma unroll
        for (int it = 0; it < 4; ++it){
            int c = tid + it * 256;
            *(bf16x8*)&Ks[c >> 4][(c & 15) * 8] = rk[it];
            *(bf16x8*)&Vt[c >> 3][(c & 7) * 8] = rv[it];
        }
    };

    int cur = chlo;
    while (cur < chhi && !needed(cur)) ++cur;
    if (cur < chhi){
        LOADC(cur); STOREC(); __syncthreads();

        while (cur < chhi){
            int nxt = cur + 1;
            while (nxt < chhi && !needed(nxt)) ++nxt;
            const bool more = (nxt < chhi);
            if (more) LOADC(nxt);

            // ---- shared QK^T ----
            f32x4 sacc[4] = {};
            #pragma unroll
            for (int kk = 0; kk < 4; ++kk)
                #pragma unroll
                for (int nt = 0; nt < 4; ++nt){
                    bf16x8 kfr = *(const bf16x8*)&Ks[nt * 16 + cc][kk * 32 + g * 8];
                    sacc[nt] = mfma16(qfrag[kk], kfr, sacc[nt]);
                }

            // ---- fixed-max exp (exp2 domain), shared by both branches ----
            float pe[4][4];
            #pragma unroll
            for (int j = 0; j < 4; ++j)
                #pragma unroll
                for (int nt = 0; nt < 4; ++nt)
                    pe[j][nt] = exp2f(sacc[nt][j] * SCL2E);

            const int tbase = cur * 64;

            // ---- SEL branch (skip if no block of this chunk is selected) ----
            if (((um >> (2 * cur)) & 3ULL) != 0ULL){
                #pragma unroll
                for (int j = 0; j < 4; ++j){
                    const int iq = mrow[j];
                    const int row = g * 4 + j;
                    float pacc = 0.f;
                    #pragma unroll
                    for (int nt = 0; nt < 4; ++nt){
                        int t = tbase + nt * 16 + cc;
                        bool o = (t <= iq) && (((bm[j] >> (t >> 5)) & 1ULL) != 0ULL);
                        float p = o ? pe[j][nt] : 0.f;
                        pacc += p;
                        Ps[w][row][nt * 16 + cc] = (short)f2bfu(p);
                    }
                    lsumS[j] += pacc;
                }
                #pragma unroll
                for (int kk = 0; kk < 2; ++kk){
                    bf16x8 pa = *(const bf16x8*)&Ps[w][cc][kk * 32 + g * 8];
                    #pragma unroll
                    for (int nt2 = 0; nt2 < 8; ++nt2){
                        bf16x8 vfr = *(const bf16x8*)&Vt[nt2 * 16 + cc][kk * 32 + g * 8];
                        oaccS[nt2] = mfma16(pa, vfr, oaccS[nt2]);
                    }
                }
            }

            // ---- WIN branch (chunks qt-8 .. qt) ----
            if (cur >= qt - 8){
                #pragma unroll
                for (int j = 0; j < 4; ++j){
                    const int iq = mrow[j];
                    const int row = g * 4 + j;
                    float pacc = 0.f;
                    #pragma unroll
                    for (int nt = 0; nt < 4; ++nt){
                        int t = tbase + nt * 16 + cc;
                        bool o = (t <= iq) && ((iq - t) < 512);
                        float p = o ? pe[j][nt] : 0.f;
                        pacc += p;
                        Ps[w][row][nt * 16 + cc] = (short)f2bfu(p);
                    }
                    lsumW[j] += pacc;
                }
                #pragma unroll
                for (int kk = 0; kk < 2; ++kk){
                    bf16x8 pa = *(const bf16x8*)&Ps[w][cc][kk * 32 + g * 8];
                    #pragma unroll
                    for (int nt2 = 0; nt2 < 8; ++nt2){
                        bf16x8 vfr = *(const bf16x8*)&Vt[nt2 * 16 + cc][kk * 32 + g * 8];
                        oaccW[nt2] = mfma16(pa, vfr, oaccW[nt2]);
                    }
                }
            }

            __syncthreads();                // all waves done reading Ks/Vt
            if (more){ STOREC(); __syncthreads(); }
            cur = more ? nxt : chhi;
        }
    }

    // ---- epilogue: plain bf16 slot stores for O; f32 atomics for l ----
    {
        size_t sb = (((size_t)h * 80 + rr) * 64) * 128;
        #pragma unroll
        for (int j = 0; j < 4; ++j){
            int row = w * 16 + g * 4 + j;
            #pragma unroll
            for (int nt2 = 0; nt2 < 8; ++nt2)
                Psel[sb + (size_t)row * 128 + nt2 * 16 + cc] = f2bfu(oaccS[nt2][j]);
        }
    }
    int wslot = (seg == nseg - 1) ? 1 : ((seg == nseg - 2) ? 0 : -1);
    if (wslot >= 0){
        int wunit = (qt < 8) ? qt : 8 + (qt - 8) * 2 + wslot;
        size_t wb = (((size_t)h * 56 + wunit) * 64) * 128;
        #pragma unroll
        for (int j = 0; j < 4; ++j){
            int row = w * 16 + g * 4 + j;
            #pragma unroll
            for (int nt2 = 0; nt2 < 8; ++nt2)
                Pwin[wb + (size_t)row * 128 + nt2 * 16 + cc] = f2bfu(oaccW[nt2][j]);
        }
    }
    #pragma unroll
    for (int j = 0; j < 4; ++j){
        const int iq = mrow[j];
        float ls = lsumS[j], lw = lsumW[j];
        #pragma unroll
        for (int off = 1; off < 16; off <<= 1){
            ls += __shfl_xor(ls, off);
            lw += __shfl_xor(lw, off);
        }
        if (cc == 0){
            atomicAdd(&lsel[(size_t)h * 2048 + iq], ls);
            atomicAdd(&lwin[(size_t)h * 2048 + iq], lw);
        }
    }
}

// ---------------------------------------------------------------------------
// Finalize: gather <=4 sel slots + <=2 win slots, normalize, gate, add.
// ---------------------------------------------------------------------------
__global__ __launch_bounds__(256) void finalize(
    const unsigned short* __restrict__ Psel, const float* __restrict__ lsel,
    const unsigned short* __restrict__ Pwin, const float* __restrict__ lwin,
    const float* __restrict__ gates, float* __restrict__ out)
{
    int idx = blockIdx.x * 256 + (int)threadIdx.x;   // 0..1048575
    int d4 = (idx & 31) * 4;
    int s  = (idx >> 5) & 2047;
    int h  = idx >> 16;
    int qt = s >> 6, row = s & 63;
    int g4 = qt >> 3, nseg = g4 + 1;
    int rr0 = 4 * g4 * (g4 + 1) + (qt - 8 * g4) * nseg;

    float ax = 0.f, ay = 0.f, az = 0.f, aw = 0.f;
    for (int sg = 0; sg < nseg; ++sg){
        s16x4 v = *(const s16x4*)&Psel[(((size_t)h * 80 + rr0 + sg) * 64 + row) * 128 + d4];
        ax += bf2f((unsigned short)v[0]); ay += bf2f((unsigned short)v[1]);
        az += bf2f((unsigned short)v[2]); aw += bf2f((unsigned short)v[3]);
    }
    float bx = 0.f, by = 0.f, bz = 0.f, bw = 0.f;
    {
        int u1 = (qt < 8) ? qt : 8 + (qt - 8) * 2 + 1;
        s16x4 v = *(const s16x4*)&Pwin[(((size_t)h * 56 + u1) * 64 + row) * 128 + d4];
        bx = bf2f((unsigned short)v[0]); by = bf2f((unsigned short)v[1]);
        bz = bf2f((unsigned short)v[2]); bw = bf2f((unsigned short)v[3]);
        if (qt >= 8){
            int u0 = 8 + (qt - 8) * 2;
            s16x4 v0 = *(const s16x4*)&Pwin[(((size_t)h * 56 + u0) * 64 + row) * 128 + d4];
            bx += bf2f((unsigned short)v0[0]); by += bf2f((unsigned short)v0[1]);
            bz += bf2f((unsigned short)v0[2]); bw += bf2f((unsigned short)v0[3]);
        }
    }
    size_t hs = (size_t)h * 2048 + s;
    float g1 = gates[hs * 3 + 1], g2 = gates[hs * 3 + 2];
    float il = g1 / lsel[hs];
    float iw = g2 / lwin[hs];
    float* op = &out[(size_t)s * 2048 + h * 128 + d4];
    float4 o = *(const float4*)op;
    o.x += ax * il + bx * iw;
    o.y += ay * il + by * iw;
    o.z += az * il + bz * iw;
    o.w += aw * il + bw * iw;
    *(float4*)op = o;
}

// ---------------------------------------------------------------------------
extern "C" void kernel_launch(void* const* d_in, const int* in_sizes, int n_in,
                              void* d_out, int out_size, void* d_ws, size_t ws_size,
                              hipStream_t stream)
{
    const float* X  = (const float*)d_in[0];
    const float* Wq = (const float*)d_in[1];
    const float* bq = (const float*)d_in[2];
    const float* Wk = (const float*)d_in[3];
    const float* bk = (const float*)d_in[4];
    const float* Wv = (const float*)d_in[5];
    const float* bv = (const float*)d_in[6];
    const float* Wg = (const float*)d_in[7];
    const float* bg = (const float*)d_in[8];
    float* out = (float*)d_out;

    const size_t MBs = (size_t)1 << 20;
    char* ws = (char*)d_ws;

    unsigned short* Xh  = (unsigned short*)(ws + 0 * MBs);
    unsigned short* Xl  = (unsigned short*)(ws + 8 * MBs);
    unsigned short* WTh = (unsigned short*)(ws + 16 * MBs);
    unsigned short* WTl = (unsigned short*)(ws + 24 * MBs);
    float* qf  = (float*)(ws + 32 * MBs);
    float* kf  = (float*)(ws + 48 * MBs);
    unsigned short* vtbf = (unsigned short*)(ws + 64 * MBs);
    unsigned short* qbf  = (unsigned short*)(ws + 16 * MBs);  // alias (W dead)
    unsigned short* kbf  = (unsigned short*)(ws + 24 * MBs);  // alias
    // attn partial slots (aliases of regions dead by attn_fd time):
    unsigned short* PselB = (unsigned short*)(ws + 32 * MBs); // 21 MB (qf/kf dead)
    unsigned short* PwinB = (unsigned short*)(ws + 0 * MBs);  // 14.7 MB (Xh/Xl dead)
    const size_t SM = 72 * MBs;
    float* cost  = (float*)(ws + SM);
    float* sint  = (float*)(ws + SM + 524288);
    float* kcmp  = (float*)(ws + SM + 1048576);
    float* vcmp  = (float*)(ws + SM + 1572864);
    float* gatesb = (float*)(ws + SM + 2097152);
    unsigned long long* bmaskb = (unsigned long long*)(ws + SM + 2490368);
    float* lsel = (float*)(ws + SM + 2752512);
    float* lwin = (float*)(ws + SM + 2883584);   // ends ~72MB+2.9MB

    rope_table_k<<<2048, 64, 0, stream>>>(cost, sint);
    prep_split<<<4096, 256, 0, stream>>>(X, Xh, Xl);

    prep_wT<<<dim3(32, 32), 256, 0, stream>>>(Wq, WTh, WTl);
    gemm_bf<2><<<256, 256, 0, stream>>>(Xh, Xl, WTh, WTl, bq, qf, nullptr);
    prep_wT<<<dim3(32, 32), 256, 0, stream>>>(Wk, WTh, WTl);
    gemm_bf<2><<<256, 256, 0, stream>>>(Xh, Xl, WTh, WTl, bk, kf, nullptr);
    prep_wT<<<dim3(32, 32), 256, 0, stream>>>(Wv, WTh, nullptr);
    gemm_bf<1><<<256, 256, 0, stream>>>(Xh, nullptr, WTh, nullptr, bv, nullptr, vtbf);

    rope_apply<<<16384, 256, 0, stream>>>(qf, kf, qbf, kbf, cost, sint);
    cmp_mean<<<512, 256, 0, stream>>>(kf, vtbf, kcmp, vcmp);
    cmp_attn<<<dim3(32, 16), 256, 0, stream>>>(qf, kcmp, vcmp, Wg, bg,
                                               out, gatesb, bmaskb);

    // zero the tiny l partials only (O slots are written unconditionally)
    hipMemsetAsync(lsel, 0, 262144, stream);

    attn_fd<<<1280, 256, 0, stream>>>(qbf, kbf, vtbf, bmaskb,
                                      PselB, PwinB, lsel, lwin);
    finalize<<<4096, 256, 0, stream>>>(PselB, lsel, PwinB, lwin, gatesb, out);
}